// Round 3
// baseline (335.438 us; speedup 1.0000x reference)
//
#include <hip/hip_runtime.h>
#include <stdint.h>

#define BATCH 4
#define SEQ   1024
#define NHEAD 16
#define DHEAD 128
#define HDIM  2048
#define GM    4096   /* BATCH*SEQ */
#define GK    2048
#define NT    32     /* GK/64 K-tiles */

typedef __attribute__((ext_vector_type(8))) short short8;
typedef __attribute__((ext_vector_type(4))) float f32x4;

__device__ __forceinline__ uint16_t f2bf(float f) {
  uint32_t u = __builtin_bit_cast(uint32_t, f);
  u += 0x7fffu + ((u >> 16) & 1u);
  return (uint16_t)(u >> 16);
}
__device__ __forceinline__ float bf2f(uint16_t h) {
  return __builtin_bit_cast(float, (uint32_t)h << 16);
}

// XOR swizzles (involutions) for rowlen-128B and -256B LDS tiles
__device__ __forceinline__ uint32_t swz128(uint32_t a) { return a ^ (((a >> 7) & 7u) << 4); }
__device__ __forceinline__ uint32_t swz256(uint32_t a) { return a ^ (((a >> 8) & 7u) << 4); }

#define GAS __attribute__((address_space(1)))
#define LAS __attribute__((address_space(3)))
__device__ __forceinline__ void gload_lds16(const void* g, void* l) {
  // LDS dest = wave-uniform base (HW adds lane*16); global src is per-lane.
  __builtin_amdgcn_global_load_lds((GAS const void*)g, (LAS void*)l, 16, 0, 0);
}

#define SBAR  do { __builtin_amdgcn_s_barrier(); __builtin_amdgcn_sched_barrier(0); } while (0)
#define LGKM0 do { asm volatile("s_waitcnt lgkmcnt(0)" ::: "memory"); __builtin_amdgcn_sched_barrier(0); } while (0)
#define VM2   do { asm volatile("s_waitcnt vmcnt(2)" ::: "memory"); __builtin_amdgcn_sched_barrier(0); } while (0)
#define VM0   do { asm volatile("s_waitcnt vmcnt(0)" ::: "memory"); __builtin_amdgcn_sched_barrier(0); } while (0)

// ---------------- fp32 -> bf16 converts ----------------
__global__ void cvt_kernel(const float* __restrict__ in, uint16_t* __restrict__ out, int n8) {
  int i = blockIdx.x * 256 + threadIdx.x;
  if (i >= n8) return;
  const float4* p = (const float4*)in + (size_t)i * 2;
  float4 a = p[0], b = p[1];
  uint32_t w0 = f2bf(a.x) | ((uint32_t)f2bf(a.y) << 16);
  uint32_t w1 = f2bf(a.z) | ((uint32_t)f2bf(a.w) << 16);
  uint32_t w2 = f2bf(b.x) | ((uint32_t)f2bf(b.y) << 16);
  uint32_t w3 = f2bf(b.z) | ((uint32_t)f2bf(b.w) << 16);
  int4 r; r.x = (int)w0; r.y = (int)w1; r.z = (int)w2; r.w = (int)w3;
  *(int4*)(out + (size_t)i * 8) = r;
}

__global__ void cvtw_kernel(const float* __restrict__ W0, const float* __restrict__ W1,
                            const float* __restrict__ W2, const float* __restrict__ W3,
                            uint16_t* __restrict__ out) {
  const float* src = (blockIdx.y == 0) ? W0 : (blockIdx.y == 1) ? W1 : (blockIdx.y == 2) ? W2 : W3;
  int i = blockIdx.x * 256 + threadIdx.x;
  const float4* p = (const float4*)src + (size_t)i * 2;
  float4 a = p[0], b = p[1];
  uint32_t w0 = f2bf(a.x) | ((uint32_t)f2bf(a.y) << 16);
  uint32_t w1 = f2bf(a.z) | ((uint32_t)f2bf(a.w) << 16);
  uint32_t w2 = f2bf(b.x) | ((uint32_t)f2bf(b.y) << 16);
  uint32_t w3 = f2bf(b.z) | ((uint32_t)f2bf(b.w) << 16);
  int4 r; r.x = (int)w0; r.y = (int)w1; r.z = (int)w2; r.w = (int)w3;
  *(int4*)(out + (size_t)blockIdx.y * HDIM * HDIM + (size_t)i * 8) = r;
}

// ---------------- 256x256 8-phase GEMM: C = A(MxK) @ W(NxK)^T + bias ----------------
// BM=BN=256, BK=64. 512 thr = 8 waves (2M x 4N), per-wave 128x64 = acc[8][4].
// LDS 128KB: A[2][256][64] + B[2][256][64] bf16, 128B rows, XOR-swizzled.
// Per K-tile t, 4 phases x 16 MFMA:
//   p1: read A(mi0-3)+B(nj0-1); stage Ah1(t+1); MFMA q(0,0)
//   p2: read B(nj2-3);          stage Bh0(t+1); MFMA q(0,1)
//   p3: read A(mi4-7);          stage Bh1(t+1); MFMA q(1,0)
//   p4:                          stage Ah0(t+2); MFMA q(1,1); vmcnt(2)
// Only p4's stage hits the buffer being read (Ah0, fully read after p3). vmcnt never 0.
// MODE 0: bf16 out + fused rope for z<2 (q,k).  MODE 1: f32 out.
template <int MODE>
__global__ __launch_bounds__(512, 2) void gemm256_kernel(
    const uint16_t* __restrict__ A,
    const uint16_t* __restrict__ W0, const uint16_t* __restrict__ W1, const uint16_t* __restrict__ W2,
    const float* __restrict__ b0, const float* __restrict__ b1, const float* __restrict__ b2,
    const float* __restrict__ fcos, const float* __restrict__ fsin,
    void* __restrict__ o0, void* __restrict__ o1, void* __restrict__ o2) {
  __shared__ __align__(16) char ldsA[65536];
  __shared__ __align__(16) char ldsB[65536];
  const int tid = threadIdx.x, lane = tid & 63, wid = tid >> 6;
  const int c = lane & 15, g = lane >> 4;
  const int wr = wid >> 2, wc = wid & 3;              // 2M x 4N wave grid
  const int row0 = blockIdx.x * 256, col0 = blockIdx.y * 256;
  const uint16_t* W = (blockIdx.z == 0) ? W0 : (blockIdx.z == 1) ? W1 : W2;
  const float* bias = (blockIdx.z == 0) ? b0 : (blockIdx.z == 1) ? b1 : b2;

  const uint32_t colswz = ((uint32_t)((lane & 7) ^ (lane >> 3))) << 4;  // pre-swizzled src col
  const int srow = wid * 16 + (lane >> 3);            // staging row within half-tile

  auto stA = [&](int t, int h) {
    int ts = (t < NT) ? t : 0;
    char* d = ldsA + (t & 1) * 32768 + (h * 128 + wid * 16) * 128;
    const char* s = (const char*)A + ((size_t)(row0 + h * 128 + srow) * GK + (size_t)ts * 64) * 2 + colswz;
    gload_lds16(s, d);
    gload_lds16(s + (size_t)8 * GK * 2, d + 1024);
  };
  auto stB = [&](int t, int h) {
    int ts = (t < NT) ? t : 0;
    char* d = ldsB + (t & 1) * 32768 + (h * 128 + wid * 16) * 128;
    const char* s = (const char*)W + ((size_t)(col0 + h * 128 + srow) * GK + (size_t)ts * 64) * 2 + colswz;
    gload_lds16(s, d);
    gload_lds16(s + (size_t)8 * GK * 2, d + 1024);
  };
  auto ldA = [&](int buf, int row, int ks) -> short8 {
    return *(const short8*)(ldsA + buf * 32768 + row * 128 +
                            (((uint32_t)(ks * 64 + g * 16)) ^ (((uint32_t)row & 7u) << 4)));
  };
  auto ldB = [&](int buf, int row, int ks) -> short8 {
    return *(const short8*)(ldsB + buf * 32768 + row * 128 +
                            (((uint32_t)(ks * 64 + g * 16)) ^ (((uint32_t)row & 7u) << 4)));
  };

  f32x4 acc[8][4] = {};

  // prologue: tile0 complete + Ah0(1); wait tile0 (vmcnt(2) leaves Ah0(1) in flight)
  stA(0, 0); stA(0, 1); stB(0, 0); stB(0, 1); stA(1, 0);
  VM2; SBAR;

  short8 af[4][2], bL[2][2], bH[2][2];
  for (int t = 0; t < NT; ++t) {
    const int bufR = t & 1;
    // ---- p1: A lo-half frags + B lo frags; stage Ah1(t+1); MFMA quad(0,0)
#pragma unroll
    for (int mi = 0; mi < 4; ++mi)
#pragma unroll
      for (int ks = 0; ks < 2; ++ks) af[mi][ks] = ldA(bufR, wr * 128 + mi * 16 + c, ks);
#pragma unroll
    for (int nj = 0; nj < 2; ++nj)
#pragma unroll
      for (int ks = 0; ks < 2; ++ks) bL[nj][ks] = ldB(bufR, wc * 64 + nj * 16 + c, ks);
    stA(t + 1, 1);
    SBAR; LGKM0;
    __builtin_amdgcn_s_setprio(1);
#pragma unroll
    for (int mi = 0; mi < 4; ++mi)
#pragma unroll
      for (int nj = 0; nj < 2; ++nj)
#pragma unroll
        for (int ks = 0; ks < 2; ++ks)
          acc[mi][nj] = __builtin_amdgcn_mfma_f32_16x16x32_bf16(af[mi][ks], bL[nj][ks], acc[mi][nj], 0, 0, 0);
    __builtin_amdgcn_s_setprio(0);
    SBAR;
    // ---- p2: B hi frags; stage Bh0(t+1); MFMA quad(0,1)
#pragma unroll
    for (int nj = 0; nj < 2; ++nj)
#pragma unroll
      for (int ks = 0; ks < 2; ++ks) bH[nj][ks] = ldB(bufR, wc * 64 + (2 + nj) * 16 + c, ks);
    stB(t + 1, 0);
    SBAR; LGKM0;
    __builtin_amdgcn_s_setprio(1);
#pragma unroll
    for (int mi = 0; mi < 4; ++mi)
#pragma unroll
      for (int nj = 0; nj < 2; ++nj)
#pragma unroll
        for (int ks = 0; ks < 2; ++ks)
          acc[mi][2 + nj] = __builtin_amdgcn_mfma_f32_16x16x32_bf16(af[mi][ks], bH[nj][ks], acc[mi][2 + nj], 0, 0, 0);
    __builtin_amdgcn_s_setprio(0);
    SBAR;
    // ---- p3: A hi-half frags; stage Bh1(t+1); MFMA quad(1,0)
#pragma unroll
    for (int mi = 0; mi < 4; ++mi)
#pragma unroll
      for (int ks = 0; ks < 2; ++ks) af[mi][ks] = ldA(bufR, wr * 128 + (4 + mi) * 16 + c, ks);
    stB(t + 1, 1);
    SBAR; LGKM0;
    __builtin_amdgcn_s_setprio(1);
#pragma unroll
    for (int mi = 0; mi < 4; ++mi)
#pragma unroll
      for (int nj = 0; nj < 2; ++nj)
#pragma unroll
        for (int ks = 0; ks < 2; ++ks)
          acc[4 + mi][nj] = __builtin_amdgcn_mfma_f32_16x16x32_bf16(af[mi][ks], bL[nj][ks], acc[4 + mi][nj], 0, 0, 0);
    __builtin_amdgcn_s_setprio(0);
    SBAR;
    // ---- p4: stage Ah0(t+2) into read-buffer (A reads all done at p3); MFMA quad(1,1)
    stA(t + 2, 0);
    SBAR;
    __builtin_amdgcn_s_setprio(1);
#pragma unroll
    for (int mi = 0; mi < 4; ++mi)
#pragma unroll
      for (int nj = 0; nj < 2; ++nj)
#pragma unroll
        for (int ks = 0; ks < 2; ++ks)
          acc[4 + mi][2 + nj] = __builtin_amdgcn_mfma_f32_16x16x32_bf16(af[mi][ks], bH[nj][ks], acc[4 + mi][2 + nj], 0, 0, 0);
    __builtin_amdgcn_s_setprio(0);
    VM2;  // tile t+1 fully landed; only Ah0(t+2) in flight
    SBAR;
  }
  VM0;  // don't exit with loads still writing LDS

  // ---- epilogue: bias (+ rope for q/k) ----
  void* outp = (blockIdx.z == 0) ? o0 : (blockIdx.z == 1) ? o1 : o2;
  const bool dorope = (MODE == 0) && (blockIdx.z < 2);
  float bn[4];
#pragma unroll
  for (int nj = 0; nj < 4; ++nj) bn[nj] = bias[col0 + wc * 64 + nj * 16 + c];
#pragma unroll
  for (int mi = 0; mi < 8; ++mi) {
#pragma unroll
    for (int jj = 0; jj < 4; ++jj) {
      const int row = row0 + wr * 128 + mi * 16 + g * 4 + jj;
      const int s = row & (SEQ - 1);
#pragma unroll
      for (int nj = 0; nj < 4; ++nj) {
        const int d = wc * 64 + nj * 16 + c;     // col within 256-tile
        const int dh = d & (DHEAD - 1);          // head-local col (col0 % 256 == 0)
        float v = acc[mi][nj][jj] + bn[nj];
        float res = v;
        if (dorope) {
          float cs = fcos[s * 64 + (dh >> 1)];
          float sn = fsin[s * 64 + (dh >> 1)];
          float o = __shfl_xor(v, 1, 64);
          res = (c & 1) ? (o * sn + v * cs) : (v * cs - o * sn);
        }
        const size_t idx = (size_t)row * HDIM + col0 + d;
        if (MODE == 1) ((float*)outp)[idx] = res;
        else           ((uint16_t*)outp)[idx] = f2bf(res);
      }
    }
  }
}

// ---------------- flash attention (unchanged) ----------------
__global__ __launch_bounds__(256, 2) void attn_kernel(
    const uint16_t* __restrict__ q, const uint16_t* __restrict__ k,
    const uint16_t* __restrict__ v, const float* __restrict__ mask,
    uint16_t* __restrict__ ctx) {
  __shared__ __align__(16) char smQ[64 * 256];
  __shared__ __align__(16) char smK[64 * 256];
  __shared__ __align__(16) char smVT[128 * 128];
  __shared__ __align__(16) char smP[64 * 128];
  __shared__ float smMask[64];
  __shared__ float smScale[64];

  const int tid = threadIdx.x, lane = tid & 63, wid = tid >> 6;
  const int c = lane & 15, g = lane >> 4;
  const int b = blockIdx.z, h = blockIdx.y, q0 = blockIdx.x * 64;
  const float scale = 0.022097086912079608f;  // 1/sqrt(2048)

#pragma unroll
  for (int i = 0; i < 4; ++i) {
    uint32_t o = wid * 4096 + i * 1024 + lane * 16;
    uint32_t r = o >> 8;
    uint32_t cb = swz256(o) & 255;
    gload_lds16((const char*)q + ((size_t)(b * SEQ + q0 + r) * HDIM + h * DHEAD) * 2 + cb,
                smQ + wid * 4096 + i * 1024);
  }

  float mreg = -1e30f, lreg = 0.f;
  f32x4 oacc[8] = {};

  for (int t = 0; t < 16; ++t) {
    const int kv0 = t * 64;
    __syncthreads();
#pragma unroll
    for (int i = 0; i < 4; ++i) {
      uint32_t o = wid * 4096 + i * 1024 + lane * 16;
      uint32_t r = o >> 8;
      uint32_t cb = swz256(o) & 255;
      gload_lds16((const char*)k + ((size_t)(b * SEQ + kv0 + r) * HDIM + h * DHEAD) * 2 + cb,
                  smK + wid * 4096 + i * 1024);
    }
    if (tid < 64) smMask[tid] = mask[b * SEQ + kv0 + tid];
    {
      const int kvr = tid >> 2, dblk = tid & 3;
      const uint16_t* src = v + (size_t)(b * SEQ + kv0 + kvr) * HDIM + h * DHEAD + dblk * 32;
      uint16_t tmp[32];
      *(int4*)(tmp)      = *(const int4*)(src);
      *(int4*)(tmp + 8)  = *(const int4*)(src + 8);
      *(int4*)(tmp + 16) = *(const int4*)(src + 16);
      *(int4*)(tmp + 24) = *(const int4*)(src + 24);
#pragma unroll
      for (int e = 0; e < 32; ++e) {
        int d = dblk * 32 + e;
        *(uint16_t*)(smVT + swz128((uint32_t)(d * 128 + kvr * 2))) = tmp[e];
      }
    }
    __syncthreads();

    f32x4 st[4] = {};
#pragma unroll
    for (int ks = 0; ks < 4; ++ks) {
      short8 qf = *(const short8*)(smQ + swz256((uint32_t)((wid * 16 + c) * 256 + ks * 64 + g * 16)));
#pragma unroll
      for (int mi = 0; mi < 4; ++mi) {
        short8 kf = *(const short8*)(smK + swz256((uint32_t)((mi * 16 + c) * 256 + ks * 64 + g * 16)));
        st[mi] = __builtin_amdgcn_mfma_f32_16x16x32_bf16(kf, qf, st[mi], 0, 0, 0);
      }
    }
    float sv[4][4];
    float pmax = -1e30f;
#pragma unroll
    for (int mi = 0; mi < 4; ++mi) {
      float4 mb = *(const float4*)(smMask + mi * 16 + g * 4);
      float mbv[4] = {mb.x, mb.y, mb.z, mb.w};
#pragma unroll
      for (int jj = 0; jj < 4; ++jj) {
        float s = st[mi][jj] * scale;
        if (mbv[jj] == 0.f) s = -1e9f;
        sv[mi][jj] = s;
        pmax = fmaxf(pmax, s);
      }
    }
    pmax = fmaxf(pmax, __shfl_xor(pmax, 16, 64));
    pmax = fmaxf(pmax, __shfl_xor(pmax, 32, 64));
    float mnew = fmaxf(mreg, pmax);
    float fac = __expf(mreg - mnew);
    float rsum = 0.f;
    uint32_t pw[4][2];
#pragma unroll
    for (int mi = 0; mi < 4; ++mi) {
      float p0 = __expf(sv[mi][0] - mnew);
      float p1 = __expf(sv[mi][1] - mnew);
      float p2 = __expf(sv[mi][2] - mnew);
      float p3 = __expf(sv[mi][3] - mnew);
      rsum += (p0 + p1) + (p2 + p3);
      pw[mi][0] = f2bf(p0) | ((uint32_t)f2bf(p1) << 16);
      pw[mi][1] = f2bf(p2) | ((uint32_t)f2bf(p3) << 16);
    }
    rsum += __shfl_xor(rsum, 16, 64);
    rsum += __shfl_xor(rsum, 32, 64);
    lreg = lreg * fac + rsum;
    mreg = mnew;
#pragma unroll
    for (int mi = 0; mi < 4; ++mi) {
      uint32_t addr = swz128((uint32_t)((wid * 16 + c) * 128 + (mi * 16 + g * 4) * 2));
      uint2 wv; wv.x = pw[mi][0]; wv.y = pw[mi][1];
      *(uint2*)(smP + addr) = wv;
    }
    if (g == 0) smScale[wid * 16 + c] = fac;
    __syncthreads();

    float4 fv = *(const float4*)(smScale + wid * 16 + g * 4);
    float fvv[4] = {fv.x, fv.y, fv.z, fv.w};
#pragma unroll
    for (int nj = 0; nj < 8; ++nj)
#pragma unroll
      for (int jj = 0; jj < 4; ++jj) oacc[nj][jj] *= fvv[jj];
#pragma unroll
    for (int ks = 0; ks < 2; ++ks) {
      short8 pf = *(const short8*)(smP + swz128((uint32_t)((wid * 16 + c) * 128 + ks * 64 + g * 16)));
#pragma unroll
      for (int nj = 0; nj < 8; ++nj) {
        short8 vf = *(const short8*)(smVT + swz128((uint32_t)((nj * 16 + c) * 128 + ks * 64 + g * 16)));
        oacc[nj] = __builtin_amdgcn_mfma_f32_16x16x32_bf16(pf, vf, oacc[nj], 0, 0, 0);
      }
    }
  }

  __syncthreads();
  if (g == 0) smScale[wid * 16 + c] = lreg;
  __syncthreads();
  float4 lv = *(const float4*)(smScale + wid * 16 + g * 4);
  float inv[4] = {1.f / lv.x, 1.f / lv.y, 1.f / lv.z, 1.f / lv.w};
#pragma unroll
  for (int nj = 0; nj < 8; ++nj) {
#pragma unroll
    for (int jj = 0; jj < 4; ++jj) {
      int qrow = q0 + wid * 16 + g * 4 + jj;
      int dcol = h * DHEAD + nj * 16 + c;
      ctx[(size_t)(b * SEQ + qrow) * HDIM + dcol] = f2bf(oacc[nj][jj] * inv[jj]);
    }
  }
}

// ---------------- launch ----------------
extern "C" void kernel_launch(void* const* d_in, const int* in_sizes, int n_in,
                              void* d_out, int out_size, void* d_ws, size_t ws_size,
                              hipStream_t stream) {
  const float* hs   = (const float*)d_in[0];
  const float* fcos = (const float*)d_in[1];
  const float* fsin = (const float*)d_in[2];
  const float* mask = (const float*)d_in[3];
  const float* Wq = (const float*)d_in[4];  const float* bq = (const float*)d_in[5];
  const float* Wk = (const float*)d_in[6];  const float* bk = (const float*)d_in[7];
  const float* Wv = (const float*)d_in[8];  const float* bv = (const float*)d_in[9];
  const float* Wo = (const float*)d_in[10]; const float* bo = (const float*)d_in[11];
  float* out = (float*)d_out;

  char* ws = (char*)d_ws;
  const size_t XB = (size_t)GM * HDIM * 2;    // 16 MB
  const size_t WB = (size_t)HDIM * HDIM * 2;  //  8 MB
  uint16_t* Xbf = (uint16_t*)(ws);            // reused as ctx after QKV
  uint16_t* Wqb = (uint16_t*)(ws + XB);       // Wqb..Wob contiguous (cvtw relies on it)
  uint16_t* Wkb = (uint16_t*)(ws + XB + WB);
  uint16_t* Wvb = (uint16_t*)(ws + XB + 2 * WB);
  uint16_t* Wob = (uint16_t*)(ws + XB + 3 * WB);
  uint16_t* qb  = (uint16_t*)(ws + XB + 4 * WB);
  uint16_t* kb  = (uint16_t*)(ws + XB + 4 * WB + XB);
  uint16_t* vb  = (uint16_t*)(ws + XB + 4 * WB + 2 * XB);

  cvt_kernel<<<4096, 256, 0, stream>>>(hs, Xbf, (GM * HDIM) / 8);
  cvtw_kernel<<<dim3(2048, 4), 256, 0, stream>>>(Wq, Wk, Wv, Wo, Wqb);

  gemm256_kernel<0><<<dim3(GM / 256, HDIM / 256, 3), 512, 0, stream>>>(
      Xbf, Wqb, Wkb, Wvb, bq, bk, bv, fcos, fsin, qb, kb, vb);

  attn_kernel<<<dim3(SEQ / 64, NHEAD, BATCH), 256, 0, stream>>>(qb, kb, vb, mask, Xbf);

  gemm256_kernel<1><<<dim3(GM / 256, HDIM / 256, 1), 512, 0, stream>>>(
      Xbf, Wob, Wob, Wob, bo, bo, bo, fcos, fsin, out, out, out);
}

// Round 4
// 292.467 us; speedup vs baseline: 1.1469x; 1.1469x over previous
//
#include <hip/hip_runtime.h>
#include <stdint.h>

#define BATCH 4
#define SEQ   1024
#define NHEAD 16
#define DHEAD 128
#define HDIM  2048
#define GM    4096   /* BATCH*SEQ */
#define GN    2048
#define GK    2048

typedef __attribute__((ext_vector_type(8))) short short8;
typedef __attribute__((ext_vector_type(4))) float f32x4;

__device__ __forceinline__ uint16_t f2bf(float f) {
  uint32_t u = __builtin_bit_cast(uint32_t, f);
  u += 0x7fffu + ((u >> 16) & 1u);
  return (uint16_t)(u >> 16);
}
__device__ __forceinline__ float bf2f(uint16_t h) {
  return __builtin_bit_cast(float, (uint32_t)h << 16);
}

// XOR swizzles (involutions): spread 16B granules across bank quads.
__device__ __forceinline__ uint32_t swz64(uint32_t a)  { return a ^ (((a >> 7) & 3u) << 4); }
__device__ __forceinline__ uint32_t swz128(uint32_t a) { return a ^ (((a >> 7) & 7u) << 4); }
__device__ __forceinline__ uint32_t swz256(uint32_t a) { return a ^ (((a >> 8) & 7u) << 4); }

#define GAS __attribute__((address_space(1)))
#define LAS __attribute__((address_space(3)))
__device__ __forceinline__ void gload_lds16(const void* g, void* l) {
  // LDS dest = wave-uniform base (HW adds lane*16); global src is per-lane.
  __builtin_amdgcn_global_load_lds((GAS const void*)g, (LAS void*)l, 16, 0, 0);
}

// ---------------- fp32 -> bf16 converts ----------------
__global__ void cvt_kernel(const float* __restrict__ in, uint16_t* __restrict__ out, int n8) {
  int i = blockIdx.x * 256 + threadIdx.x;
  if (i >= n8) return;
  const float4* p = (const float4*)in + (size_t)i * 2;
  float4 a = p[0], b = p[1];
  uint32_t w0 = f2bf(a.x) | ((uint32_t)f2bf(a.y) << 16);
  uint32_t w1 = f2bf(a.z) | ((uint32_t)f2bf(a.w) << 16);
  uint32_t w2 = f2bf(b.x) | ((uint32_t)f2bf(b.y) << 16);
  uint32_t w3 = f2bf(b.z) | ((uint32_t)f2bf(b.w) << 16);
  int4 r; r.x = (int)w0; r.y = (int)w1; r.z = (int)w2; r.w = (int)w3;
  *(int4*)(out + (size_t)i * 8) = r;
}

__global__ void cvtw_kernel(const float* __restrict__ W0, const float* __restrict__ W1,
                            const float* __restrict__ W2, const float* __restrict__ W3,
                            uint16_t* __restrict__ out) {
  const float* src = (blockIdx.y == 0) ? W0 : (blockIdx.y == 1) ? W1 : (blockIdx.y == 2) ? W2 : W3;
  int i = blockIdx.x * 256 + threadIdx.x;
  const float4* p = (const float4*)src + (size_t)i * 2;
  float4 a = p[0], b = p[1];
  uint32_t w0 = f2bf(a.x) | ((uint32_t)f2bf(a.y) << 16);
  uint32_t w1 = f2bf(a.z) | ((uint32_t)f2bf(a.w) << 16);
  uint32_t w2 = f2bf(b.x) | ((uint32_t)f2bf(b.y) << 16);
  uint32_t w3 = f2bf(b.z) | ((uint32_t)f2bf(b.w) << 16);
  int4 r; r.x = (int)w0; r.y = (int)w1; r.z = (int)w2; r.w = (int)w3;
  *(int4*)(out + (size_t)blockIdx.y * HDIM * HDIM + (size_t)i * 8) = r;
}

// ---------------- GEMM (r1 structure, measured 790 TF): C = A @ W^T + bias ----------------
// 128x128 tile, BK=32, 4 waves 2x2, 16x16x32 bf16 MFMA, global_load_lds staging.
// MODE 0: bf16 out, fused rope when blockIdx.z<2.  MODE 1: f32 out.
template <int MODE>
__device__ __forceinline__ void gemm_body(const uint16_t* __restrict__ A,
                                          const uint16_t* __restrict__ Bw,
                                          const float* __restrict__ bias,
                                          const float* __restrict__ fcos,
                                          const float* __restrict__ fsin,
                                          bool dorope,
                                          void* __restrict__ Cout) {
  __shared__ __align__(16) char smA[128 * 64];
  __shared__ __align__(16) char smB[128 * 64];
  const int tid = threadIdx.x, lane = tid & 63, wid = tid >> 6;
  const int c = lane & 15, g = lane >> 4;
  const int row0 = blockIdx.x * 128, col0 = blockIdx.y * 128;
  const int wr = wid >> 1, wc = wid & 1;
  f32x4 acc[4][4] = {};
  const uint32_t oBase = wid * 2048 + lane * 16;

  for (int kk = 0; kk < GK; kk += 32) {
#pragma unroll
    for (int q = 0; q < 2; ++q) {
      uint32_t o = oBase + q * 1024;
      uint32_t r = o >> 6;
      uint32_t cb = swz64(o) & 63;  // pre-swizzled source -> linear dest
      gload_lds16((const char*)A + ((size_t)(row0 + r) * GK + kk) * 2 + cb,
                  smA + wid * 2048 + q * 1024);
      gload_lds16((const char*)Bw + ((size_t)(col0 + r) * GK + kk) * 2 + cb,
                  smB + wid * 2048 + q * 1024);
    }
    __syncthreads();
    short8 af[4], bf[4];
#pragma unroll
    for (int m = 0; m < 4; ++m)
      af[m] = *(const short8*)(smA + swz64((uint32_t)((wr * 64 + m * 16 + c) * 64 + g * 16)));
#pragma unroll
    for (int n = 0; n < 4; ++n)
      bf[n] = *(const short8*)(smB + swz64((uint32_t)((wc * 64 + n * 16 + c) * 64 + g * 16)));
#pragma unroll
    for (int m = 0; m < 4; ++m)
#pragma unroll
      for (int n = 0; n < 4; ++n)
        acc[m][n] = __builtin_amdgcn_mfma_f32_16x16x32_bf16(af[m], bf[n], acc[m][n], 0, 0, 0);
    __syncthreads();
  }

  float bn[4];
#pragma unroll
  for (int n = 0; n < 4; ++n) bn[n] = bias[col0 + wc * 64 + n * 16 + c];
#pragma unroll
  for (int m = 0; m < 4; ++m) {
#pragma unroll
    for (int jj = 0; jj < 4; ++jj) {
      const int row = row0 + wr * 64 + m * 16 + g * 4 + jj;
      const int s = row & (SEQ - 1);
#pragma unroll
      for (int n = 0; n < 4; ++n) {
        const int d = wc * 64 + n * 16 + c;      // col within 128-tile == head-local col
        float v = acc[m][n][jj] + bn[n];
        float res = v;
        if (dorope) {
          float cs = fcos[s * 64 + (d >> 1)];
          float sn = fsin[s * 64 + (d >> 1)];
          float o = __shfl_xor(v, 1, 64);
          res = (c & 1) ? (o * sn + v * cs) : (v * cs - o * sn);
        }
        const size_t idx = (size_t)row * GN + col0 + d;
        if (MODE == 1) ((float*)Cout)[idx] = res;
        else           ((uint16_t*)Cout)[idx] = f2bf(res);
      }
    }
  }
}

__global__ __launch_bounds__(256, 2) void gemm_qkv_kernel(
    const uint16_t* __restrict__ X,
    const uint16_t* __restrict__ Wq, const uint16_t* __restrict__ Wk, const uint16_t* __restrict__ Wv,
    const float* __restrict__ bq, const float* __restrict__ bk, const float* __restrict__ bv,
    const float* __restrict__ fcos, const float* __restrict__ fsin,
    uint16_t* __restrict__ qo, uint16_t* __restrict__ ko, uint16_t* __restrict__ vo) {
  const uint16_t* W; const float* bias; uint16_t* out;
  if (blockIdx.z == 0)      { W = Wq; bias = bq; out = qo; }
  else if (blockIdx.z == 1) { W = Wk; bias = bk; out = ko; }
  else                      { W = Wv; bias = bv; out = vo; }
  gemm_body<0>(X, W, bias, fcos, fsin, blockIdx.z < 2, out);
}

__global__ __launch_bounds__(256, 2) void gemm_out_kernel(
    const uint16_t* __restrict__ ctx, const uint16_t* __restrict__ Wo,
    const float* __restrict__ bo, float* __restrict__ out) {
  gemm_body<1>(ctx, Wo, bo, nullptr, nullptr, false, out);
}

// ---------------- flash attention v2 ----------------
// block = (64 q-rows, head, batch); 4 waves x 16 q-rows.
// Q hoisted to registers (no smQ). V transposed via vectorized b128 writes.
// LDS ~48.5KB -> 3 blocks/CU.
__global__ __launch_bounds__(256, 2) void attn_kernel(
    const uint16_t* __restrict__ q, const uint16_t* __restrict__ k,
    const uint16_t* __restrict__ v, const float* __restrict__ mask,
    uint16_t* __restrict__ ctx) {
  __shared__ __align__(16) char smK[64 * 256];    // [kv][256B] swz256
  __shared__ __align__(16) char smVT[128 * 128];  // [d][128B]  swz128
  __shared__ __align__(16) char smP[64 * 128];    // [q][128B]  swz128
  __shared__ float smMask[64];
  __shared__ float smScale[64];

  const int tid = threadIdx.x, lane = tid & 63, wid = tid >> 6;
  const int c = lane & 15, g = lane >> 4;
  const int b = blockIdx.z, h = blockIdx.y, q0 = blockIdx.x * 64;
  const float scale = 0.022097086912079608f;  // 1/sqrt(2048)

  // ---- Q hoist: this lane's q-col fragments, d = ks*32 + g*8 .. +7
  short8 qreg[4];
  {
    const uint16_t* qrow = q + (size_t)(b * SEQ + q0 + wid * 16 + c) * HDIM + h * DHEAD;
#pragma unroll
    for (int ks = 0; ks < 4; ++ks) qreg[ks] = *(const short8*)(qrow + ks * 32 + g * 8);
  }

  // V-transpose thread mapping: 8 kv x 4 d per thread
  const int kvg = tid >> 5;          // 0..7  -> kv = kvg*8 .. +7
  const int d0  = (tid & 31) * 4;    // 0..124

  float mreg = -1e30f, lreg = 0.f;
  f32x4 oacc[8] = {};

  for (int t = 0; t < 16; ++t) {
    const int kv0 = t * 64;
    __syncthreads();  // prior tile's LDS reads done
    // stage K tile (global_load_lds, pre-swizzled source)
#pragma unroll
    for (int i = 0; i < 4; ++i) {
      uint32_t o = wid * 4096 + i * 1024 + lane * 16;
      uint32_t r = o >> 8;
      uint32_t cb = swz256(o) & 255;
      gload_lds16((const char*)k + ((size_t)(b * SEQ + kv0 + r) * HDIM + h * DHEAD) * 2 + cb,
                  smK + wid * 4096 + i * 1024);
    }
    if (tid < 64) smMask[tid] = mask[b * SEQ + kv0 + tid];
    {  // V transpose: 8 x 8B loads, 4 x b128 LDS writes
      const uint16_t* vsrc = v + (size_t)(b * SEQ + kv0 + kvg * 8) * HDIM + h * DHEAD + d0;
      uint32_t vw[8][2];
#pragma unroll
      for (int e = 0; e < 8; ++e) {
        uint2 t2 = *(const uint2*)(vsrc + (size_t)e * HDIM);
        vw[e][0] = t2.x; vw[e][1] = t2.y;
      }
#pragma unroll
      for (int j = 0; j < 4; ++j) {
        const int hw = j >> 1, sh = (j & 1) * 16;
        int4 pk;
        pk.x = (int)(((vw[0][hw] >> sh) & 0xffffu) | (((vw[1][hw] >> sh) & 0xffffu) << 16));
        pk.y = (int)(((vw[2][hw] >> sh) & 0xffffu) | (((vw[3][hw] >> sh) & 0xffffu) << 16));
        pk.z = (int)(((vw[4][hw] >> sh) & 0xffffu) | (((vw[5][hw] >> sh) & 0xffffu) << 16));
        pk.w = (int)(((vw[6][hw] >> sh) & 0xffffu) | (((vw[7][hw] >> sh) & 0xffffu) << 16));
        *(int4*)(smVT + swz128((uint32_t)((d0 + j) * 128 + kvg * 16))) = pk;
      }
    }
    __syncthreads();

    // ST = K @ Q^T : lane holds 16 kv-values of q-col (wid*16+c)
    f32x4 st[4] = {};
#pragma unroll
    for (int ks = 0; ks < 4; ++ks) {
#pragma unroll
      for (int mi = 0; mi < 4; ++mi) {
        short8 kf = *(const short8*)(smK + swz256((uint32_t)((mi * 16 + c) * 256 + ks * 64 + g * 16)));
        st[mi] = __builtin_amdgcn_mfma_f32_16x16x32_bf16(kf, qreg[ks], st[mi], 0, 0, 0);
      }
    }
    float sv[4][4];
    float pmax = -1e30f;
#pragma unroll
    for (int mi = 0; mi < 4; ++mi) {
      float4 mb = *(const float4*)(smMask + mi * 16 + g * 4);
      float mbv[4] = {mb.x, mb.y, mb.z, mb.w};
#pragma unroll
      for (int jj = 0; jj < 4; ++jj) {
        float s = st[mi][jj] * scale;
        if (mbv[jj] == 0.f) s = -1e9f;
        sv[mi][jj] = s;
        pmax = fmaxf(pmax, s);
      }
    }
    pmax = fmaxf(pmax, __shfl_xor(pmax, 16, 64));
    pmax = fmaxf(pmax, __shfl_xor(pmax, 32, 64));
    float mnew = fmaxf(mreg, pmax);
    float fac = __expf(mreg - mnew);
    float rsum = 0.f;
    uint32_t pw[4][2];
#pragma unroll
    for (int mi = 0; mi < 4; ++mi) {
      float p0 = __expf(sv[mi][0] - mnew);
      float p1 = __expf(sv[mi][1] - mnew);
      float p2 = __expf(sv[mi][2] - mnew);
      float p3 = __expf(sv[mi][3] - mnew);
      rsum += (p0 + p1) + (p2 + p3);
      pw[mi][0] = f2bf(p0) | ((uint32_t)f2bf(p1) << 16);
      pw[mi][1] = f2bf(p2) | ((uint32_t)f2bf(p3) << 16);
    }
    rsum += __shfl_xor(rsum, 16, 64);
    rsum += __shfl_xor(rsum, 32, 64);
    lreg = lreg * fac + rsum;
    mreg = mnew;
#pragma unroll
    for (int mi = 0; mi < 4; ++mi) {
      uint32_t addr = swz128((uint32_t)((wid * 16 + c) * 128 + (mi * 16 + g * 4) * 2));
      uint2 wv; wv.x = pw[mi][0]; wv.y = pw[mi][1];
      *(uint2*)(smP + addr) = wv;
    }
    if (g == 0) smScale[wid * 16 + c] = fac;
    __syncthreads();  // P + scale visible

    // O rescale, then O += P @ V
    float4 fv = *(const float4*)(smScale + wid * 16 + g * 4);
    float fvv[4] = {fv.x, fv.y, fv.z, fv.w};
#pragma unroll
    for (int nj = 0; nj < 8; ++nj)
#pragma unroll
      for (int jj = 0; jj < 4; ++jj) oacc[nj][jj] *= fvv[jj];
#pragma unroll
    for (int ks = 0; ks < 2; ++ks) {
      short8 pf = *(const short8*)(smP + swz128((uint32_t)((wid * 16 + c) * 128 + ks * 64 + g * 16)));
#pragma unroll
      for (int nj = 0; nj < 8; ++nj) {
        short8 vf = *(const short8*)(smVT + swz128((uint32_t)((nj * 16 + c) * 128 + ks * 64 + g * 16)));
        oacc[nj] = __builtin_amdgcn_mfma_f32_16x16x32_bf16(pf, vf, oacc[nj], 0, 0, 0);
      }
    }
  }

  __syncthreads();
  if (g == 0) smScale[wid * 16 + c] = lreg;
  __syncthreads();
  float4 lv = *(const float4*)(smScale + wid * 16 + g * 4);
  float inv[4] = {1.f / lv.x, 1.f / lv.y, 1.f / lv.z, 1.f / lv.w};
#pragma unroll
  for (int nj = 0; nj < 8; ++nj) {
#pragma unroll
    for (int jj = 0; jj < 4; ++jj) {
      int qrow = q0 + wid * 16 + g * 4 + jj;
      int dcol = h * DHEAD + nj * 16 + c;
      ctx[(size_t)(b * SEQ + qrow) * HDIM + dcol] = f2bf(oacc[nj][jj] * inv[jj]);
    }
  }
}

// ---------------- launch ----------------
extern "C" void kernel_launch(void* const* d_in, const int* in_sizes, int n_in,
                              void* d_out, int out_size, void* d_ws, size_t ws_size,
                              hipStream_t stream) {
  const float* hs   = (const float*)d_in[0];
  const float* fcos = (const float*)d_in[1];
  const float* fsin = (const float*)d_in[2];
  const float* mask = (const float*)d_in[3];
  const float* Wq = (const float*)d_in[4];  const float* bq = (const float*)d_in[5];
  const float* Wk = (const float*)d_in[6];  const float* bk = (const float*)d_in[7];
  const float* Wv = (const float*)d_in[8];  const float* bv = (const float*)d_in[9];
  const float* Wo = (const float*)d_in[10]; const float* bo = (const float*)d_in[11];
  float* out = (float*)d_out;

  char* ws = (char*)d_ws;
  const size_t XB = (size_t)GM * HDIM * 2;    // 16 MB
  const size_t WB = (size_t)HDIM * HDIM * 2;  //  8 MB
  uint16_t* Xbf = (uint16_t*)(ws);            // reused as ctx after QKV
  uint16_t* Wqb = (uint16_t*)(ws + XB);       // Wqb..Wob contiguous (cvtw relies on it)
  uint16_t* Wkb = (uint16_t*)(ws + XB + WB);
  uint16_t* Wvb = (uint16_t*)(ws + XB + 2 * WB);
  uint16_t* Wob = (uint16_t*)(ws + XB + 3 * WB);
  uint16_t* qb  = (uint16_t*)(ws + XB + 4 * WB);
  uint16_t* kb  = (uint16_t*)(ws + XB + 4 * WB + XB);
  uint16_t* vb  = (uint16_t*)(ws + XB + 4 * WB + 2 * XB);

  cvt_kernel<<<4096, 256, 0, stream>>>(hs, Xbf, (GM * HDIM) / 8);
  cvtw_kernel<<<dim3(2048, 4), 256, 0, stream>>>(Wq, Wk, Wv, Wo, Wqb);

  gemm_qkv_kernel<<<dim3(GM / 128, GN / 128, 3), 256, 0, stream>>>(
      Xbf, Wqb, Wkb, Wvb, bq, bk, bv, fcos, fsin, qb, kb, vb);

  attn_kernel<<<dim3(SEQ / 64, NHEAD, BATCH), 256, 0, stream>>>(qb, kb, vb, mask, Xbf);

  gemm_out_kernel<<<dim3(GM / 128, GN / 128, 1), 256, 0, stream>>>(Xbf, Wob, bo, out);
}

// Round 5
// 279.954 us; speedup vs baseline: 1.1982x; 1.0447x over previous
//
#include <hip/hip_runtime.h>
#include <stdint.h>

#define BATCH 4
#define SEQ   1024
#define NHEAD 16
#define DHEAD 128
#define HDIM  2048
#define GM    4096   /* BATCH*SEQ */
#define GN    2048
#define GK    2048

typedef __attribute__((ext_vector_type(8))) short short8;
typedef __attribute__((ext_vector_type(4))) float f32x4;

__device__ __forceinline__ uint16_t f2bf(float f) {
  uint32_t u = __builtin_bit_cast(uint32_t, f);
  u += 0x7fffu + ((u >> 16) & 1u);
  return (uint16_t)(u >> 16);
}
__device__ __forceinline__ float bf2f(uint16_t h) {
  return __builtin_bit_cast(float, (uint32_t)h << 16);
}

// XOR swizzles (involutions): spread 16B granules across bank quads.
__device__ __forceinline__ uint32_t swz128(uint32_t a) { return a ^ (((a >> 7) & 7u) << 4); }
__device__ __forceinline__ uint32_t swz256(uint32_t a) { return a ^ (((a >> 8) & 7u) << 4); }

#define GAS __attribute__((address_space(1)))
#define LAS __attribute__((address_space(3)))
__device__ __forceinline__ void gload_lds16(const void* g, void* l) {
  // LDS dest = wave-uniform base (HW adds lane*16); global src is per-lane.
  __builtin_amdgcn_global_load_lds((GAS const void*)g, (LAS void*)l, 16, 0, 0);
}

// ---------------- fp32 -> bf16 converts ----------------
__global__ void cvt_kernel(const float* __restrict__ in, uint16_t* __restrict__ out, int n8) {
  int i = blockIdx.x * 256 + threadIdx.x;
  if (i >= n8) return;
  const float4* p = (const float4*)in + (size_t)i * 2;
  float4 a = p[0], b = p[1];
  uint32_t w0 = f2bf(a.x) | ((uint32_t)f2bf(a.y) << 16);
  uint32_t w1 = f2bf(a.z) | ((uint32_t)f2bf(a.w) << 16);
  uint32_t w2 = f2bf(b.x) | ((uint32_t)f2bf(b.y) << 16);
  uint32_t w3 = f2bf(b.z) | ((uint32_t)f2bf(b.w) << 16);
  int4 r; r.x = (int)w0; r.y = (int)w1; r.z = (int)w2; r.w = (int)w3;
  *(int4*)(out + (size_t)i * 8) = r;
}

__global__ void cvtw_kernel(const float* __restrict__ W0, const float* __restrict__ W1,
                            const float* __restrict__ W2, const float* __restrict__ W3,
                            uint16_t* __restrict__ out) {
  const float* src = (blockIdx.y == 0) ? W0 : (blockIdx.y == 1) ? W1 : (blockIdx.y == 2) ? W2 : W3;
  int i = blockIdx.x * 256 + threadIdx.x;
  const float4* p = (const float4*)src + (size_t)i * 2;
  float4 a = p[0], b = p[1];
  uint32_t w0 = f2bf(a.x) | ((uint32_t)f2bf(a.y) << 16);
  uint32_t w1 = f2bf(a.z) | ((uint32_t)f2bf(a.w) << 16);
  uint32_t w2 = f2bf(b.x) | ((uint32_t)f2bf(b.y) << 16);
  uint32_t w3 = f2bf(b.z) | ((uint32_t)f2bf(b.w) << 16);
  int4 r; r.x = (int)w0; r.y = (int)w1; r.z = (int)w2; r.w = (int)w3;
  *(int4*)(out + (size_t)blockIdx.y * HDIM * HDIM + (size_t)i * 8) = r;
}

// ---------------- RoPE in-place on q/k (standalone; measured ~11us, HBM-bound) ----------------
__global__ void rope_kernel(uint16_t* __restrict__ qb, uint16_t* __restrict__ kb,
                            const float* __restrict__ fcos, const float* __restrict__ fsin) {
  uint32_t i = blockIdx.x * 256 + threadIdx.x;
  uint16_t* p = (blockIdx.y == 0 ? qb : kb) + (size_t)i * 8;
  uint32_t e0 = i * 8;
  uint32_t row = e0 >> 11;
  uint32_t col = e0 & 2047;
  uint32_t s = row & (SEQ - 1);
  uint32_t pi = (col & (DHEAD - 1)) >> 1;
  float4 cv = *(const float4*)(fcos + (size_t)s * 64 + pi);
  float4 sv = *(const float4*)(fsin + (size_t)s * 64 + pi);
  int4 raw = *(const int4*)p;
  uint16_t u[8]; *(int4*)u = raw;
  float cc[4] = {cv.x, cv.y, cv.z, cv.w}, ss[4] = {sv.x, sv.y, sv.z, sv.w};
#pragma unroll
  for (int t = 0; t < 4; ++t) {
    float x0 = bf2f(u[2 * t]), x1 = bf2f(u[2 * t + 1]);
    float o0 = x0 * cc[t] - x1 * ss[t];
    float o1 = x0 * ss[t] + x1 * cc[t];
    u[2 * t] = f2bf(o0); u[2 * t + 1] = f2bf(o1);
  }
  *(int4*)p = *(int4*)u;
}

// ---------------- GEMM: C = A(MxK) @ W(NxK)^T + bias ----------------
// 128x128 tile, BK=64 (32 K-steps, half the barrier drains of BK=32), 4 waves 2x2,
// 32 MFMA / K-step, global_load_lds staging (8/wave), swz128 LDS. MODE 0 bf16 / 1 f32 out.
template <int MODE>
__device__ __forceinline__ void gemm_body(const uint16_t* __restrict__ A,
                                          const uint16_t* __restrict__ Bw,
                                          const float* __restrict__ bias,
                                          void* __restrict__ Cout) {
  __shared__ __align__(16) char smA[128 * 128];
  __shared__ __align__(16) char smB[128 * 128];
  const int tid = threadIdx.x, lane = tid & 63, wid = tid >> 6;
  const int c = lane & 15, g = lane >> 4;
  const int row0 = blockIdx.x * 128, col0 = blockIdx.y * 128;
  const int wr = wid >> 1, wc = wid & 1;
  f32x4 acc[4][4] = {};
  const uint32_t oBase = wid * 4096 + lane * 16;

  for (int kk = 0; kk < GK; kk += 64) {
#pragma unroll
    for (int q = 0; q < 4; ++q) {
      uint32_t o = oBase + q * 1024;
      uint32_t r = o >> 7;
      uint32_t cb = (o & 127) ^ ((r & 7u) << 4);  // pre-swizzled source -> linear dest
      gload_lds16((const char*)A + ((size_t)(row0 + r) * GK + kk) * 2 + cb,
                  smA + wid * 4096 + q * 1024);
      gload_lds16((const char*)Bw + ((size_t)(col0 + r) * GK + kk) * 2 + cb,
                  smB + wid * 4096 + q * 1024);
    }
    __syncthreads();   // drains staging; data visible
    short8 af[4][2], bf[4][2];
#pragma unroll
    for (int m = 0; m < 4; ++m) {
      const uint32_t row = (uint32_t)(wr * 64 + m * 16 + c);
#pragma unroll
      for (int ks = 0; ks < 2; ++ks)
        af[m][ks] = *(const short8*)(smA + row * 128 + (((uint32_t)(ks * 64 + g * 16)) ^ ((row & 7u) << 4)));
    }
#pragma unroll
    for (int n = 0; n < 4; ++n) {
      const uint32_t row = (uint32_t)(wc * 64 + n * 16 + c);
#pragma unroll
      for (int ks = 0; ks < 2; ++ks)
        bf[n][ks] = *(const short8*)(smB + row * 128 + (((uint32_t)(ks * 64 + g * 16)) ^ ((row & 7u) << 4)));
    }
#pragma unroll
    for (int m = 0; m < 4; ++m)
#pragma unroll
      for (int n = 0; n < 4; ++n)
#pragma unroll
        for (int ks = 0; ks < 2; ++ks)
          acc[m][n] = __builtin_amdgcn_mfma_f32_16x16x32_bf16(af[m][ks], bf[n][ks], acc[m][n], 0, 0, 0);
    __syncthreads();   // protect LDS before next stage
  }

  float bn[4];
#pragma unroll
  for (int n = 0; n < 4; ++n) bn[n] = bias[col0 + wc * 64 + n * 16 + c];
#pragma unroll
  for (int m = 0; m < 4; ++m) {
    const int gr = row0 + wr * 64 + m * 16 + g * 4;
#pragma unroll
    for (int n = 0; n < 4; ++n) {
      const int gc = col0 + wc * 64 + n * 16 + c;
#pragma unroll
      for (int jj = 0; jj < 4; ++jj) {
        float v = acc[m][n][jj] + bn[n];
        if (MODE == 1) ((float*)Cout)[(size_t)(gr + jj) * GN + gc] = v;
        else           ((uint16_t*)Cout)[(size_t)(gr + jj) * GN + gc] = f2bf(v);
      }
    }
  }
}

__global__ __launch_bounds__(256, 2) void gemm_qkv_kernel(
    const uint16_t* __restrict__ X,
    const uint16_t* __restrict__ Wq, const uint16_t* __restrict__ Wk, const uint16_t* __restrict__ Wv,
    const float* __restrict__ bq, const float* __restrict__ bk, const float* __restrict__ bv,
    uint16_t* __restrict__ qo, uint16_t* __restrict__ ko, uint16_t* __restrict__ vo) {
  const uint16_t* W; const float* bias; uint16_t* out;
  if (blockIdx.z == 0)      { W = Wq; bias = bq; out = qo; }
  else if (blockIdx.z == 1) { W = Wk; bias = bk; out = ko; }
  else                      { W = Wv; bias = bv; out = vo; }
  gemm_body<0>(X, W, bias, out);
}

__global__ __launch_bounds__(256, 2) void gemm_out_kernel(
    const uint16_t* __restrict__ ctx, const uint16_t* __restrict__ Wo,
    const float* __restrict__ bo, float* __restrict__ out) {
  gemm_body<1>(ctx, Wo, bo, out);
}

// ---------------- flash attention v2 (r4, measured good) ----------------
__global__ __launch_bounds__(256, 2) void attn_kernel(
    const uint16_t* __restrict__ q, const uint16_t* __restrict__ k,
    const uint16_t* __restrict__ v, const float* __restrict__ mask,
    uint16_t* __restrict__ ctx) {
  __shared__ __align__(16) char smK[64 * 256];    // [kv][256B] swz256
  __shared__ __align__(16) char smVT[128 * 128];  // [d][128B]  swz128
  __shared__ __align__(16) char smP[64 * 128];    // [q][128B]  swz128
  __shared__ float smMask[64];
  __shared__ float smScale[64];

  const int tid = threadIdx.x, lane = tid & 63, wid = tid >> 6;
  const int c = lane & 15, g = lane >> 4;
  const int b = blockIdx.z, h = blockIdx.y, q0 = blockIdx.x * 64;
  const float scale = 0.022097086912079608f;  // 1/sqrt(2048)

  short8 qreg[4];
  {
    const uint16_t* qrow = q + (size_t)(b * SEQ + q0 + wid * 16 + c) * HDIM + h * DHEAD;
#pragma unroll
    for (int ks = 0; ks < 4; ++ks) qreg[ks] = *(const short8*)(qrow + ks * 32 + g * 8);
  }

  const int kvg = tid >> 5;          // 0..7  -> kv = kvg*8 .. +7
  const int d0  = (tid & 31) * 4;    // 0..124

  float mreg = -1e30f, lreg = 0.f;
  f32x4 oacc[8] = {};

  for (int t = 0; t < 16; ++t) {
    const int kv0 = t * 64;
    __syncthreads();
#pragma unroll
    for (int i = 0; i < 4; ++i) {
      uint32_t o = wid * 4096 + i * 1024 + lane * 16;
      uint32_t r = o >> 8;
      uint32_t cb = swz256(o) & 255;
      gload_lds16((const char*)k + ((size_t)(b * SEQ + kv0 + r) * HDIM + h * DHEAD) * 2 + cb,
                  smK + wid * 4096 + i * 1024);
    }
    if (tid < 64) smMask[tid] = mask[b * SEQ + kv0 + tid];
    {  // V transpose: 8 x 8B loads, 4 x b128 LDS writes
      const uint16_t* vsrc = v + (size_t)(b * SEQ + kv0 + kvg * 8) * HDIM + h * DHEAD + d0;
      uint32_t vw[8][2];
#pragma unroll
      for (int e = 0; e < 8; ++e) {
        uint2 t2 = *(const uint2*)(vsrc + (size_t)e * HDIM);
        vw[e][0] = t2.x; vw[e][1] = t2.y;
      }
#pragma unroll
      for (int j = 0; j < 4; ++j) {
        const int hw = j >> 1, sh = (j & 1) * 16;
        int4 pk;
        pk.x = (int)(((vw[0][hw] >> sh) & 0xffffu) | (((vw[1][hw] >> sh) & 0xffffu) << 16));
        pk.y = (int)(((vw[2][hw] >> sh) & 0xffffu) | (((vw[3][hw] >> sh) & 0xffffu) << 16));
        pk.z = (int)(((vw[4][hw] >> sh) & 0xffffu) | (((vw[5][hw] >> sh) & 0xffffu) << 16));
        pk.w = (int)(((vw[6][hw] >> sh) & 0xffffu) | (((vw[7][hw] >> sh) & 0xffffu) << 16));
        *(int4*)(smVT + swz128((uint32_t)((d0 + j) * 128 + kvg * 16))) = pk;
      }
    }
    __syncthreads();

    f32x4 st[4] = {};
#pragma unroll
    for (int ks = 0; ks < 4; ++ks) {
#pragma unroll
      for (int mi = 0; mi < 4; ++mi) {
        short8 kf = *(const short8*)(smK + swz256((uint32_t)((mi * 16 + c) * 256 + ks * 64 + g * 16)));
        st[mi] = __builtin_amdgcn_mfma_f32_16x16x32_bf16(kf, qreg[ks], st[mi], 0, 0, 0);
      }
    }
    float sv[4][4];
    float pmax = -1e30f;
#pragma unroll
    for (int mi = 0; mi < 4; ++mi) {
      float4 mb = *(const float4*)(smMask + mi * 16 + g * 4);
      float mbv[4] = {mb.x, mb.y, mb.z, mb.w};
#pragma unroll
      for (int jj = 0; jj < 4; ++jj) {
        float s = st[mi][jj] * scale;
        if (mbv[jj] == 0.f) s = -1e9f;
        sv[mi][jj] = s;
        pmax = fmaxf(pmax, s);
      }
    }
    pmax = fmaxf(pmax, __shfl_xor(pmax, 16, 64));
    pmax = fmaxf(pmax, __shfl_xor(pmax, 32, 64));
    float mnew = fmaxf(mreg, pmax);
    float fac = __expf(mreg - mnew);
    float rsum = 0.f;
    uint32_t pw[4][2];
#pragma unroll
    for (int mi = 0; mi < 4; ++mi) {
      float p0 = __expf(sv[mi][0] - mnew);
      float p1 = __expf(sv[mi][1] - mnew);
      float p2 = __expf(sv[mi][2] - mnew);
      float p3 = __expf(sv[mi][3] - mnew);
      rsum += (p0 + p1) + (p2 + p3);
      pw[mi][0] = f2bf(p0) | ((uint32_t)f2bf(p1) << 16);
      pw[mi][1] = f2bf(p2) | ((uint32_t)f2bf(p3) << 16);
    }
    rsum += __shfl_xor(rsum, 16, 64);
    rsum += __shfl_xor(rsum, 32, 64);
    lreg = lreg * fac + rsum;
    mreg = mnew;
#pragma unroll
    for (int mi = 0; mi < 4; ++mi) {
      uint32_t addr = swz128((uint32_t)((wid * 16 + c) * 128 + (mi * 16 + g * 4) * 2));
      uint2 wv; wv.x = pw[mi][0]; wv.y = pw[mi][1];
      *(uint2*)(smP + addr) = wv;
    }
    if (g == 0) smScale[wid * 16 + c] = fac;
    __syncthreads();

    float4 fv = *(const float4*)(smScale + wid * 16 + g * 4);
    float fvv[4] = {fv.x, fv.y, fv.z, fv.w};
#pragma unroll
    for (int nj = 0; nj < 8; ++nj)
#pragma unroll
      for (int jj = 0; jj < 4; ++jj) oacc[nj][jj] *= fvv[jj];
#pragma unroll
    for (int ks = 0; ks < 2; ++ks) {
      short8 pf = *(const short8*)(smP + swz128((uint32_t)((wid * 16 + c) * 128 + ks * 64 + g * 16)));
#pragma unroll
      for (int nj = 0; nj < 8; ++nj) {
        short8 vf = *(const short8*)(smVT + swz128((uint32_t)((nj * 16 + c) * 128 + ks * 64 + g * 16)));
        oacc[nj] = __builtin_amdgcn_mfma_f32_16x16x32_bf16(pf, vf, oacc[nj], 0, 0, 0);
      }
    }
  }

  __syncthreads();
  if (g == 0) smScale[wid * 16 + c] = lreg;
  __syncthreads();
  float4 lv = *(const float4*)(smScale + wid * 16 + g * 4);
  float inv[4] = {1.f / lv.x, 1.f / lv.y, 1.f / lv.z, 1.f / lv.w};
#pragma unroll
  for (int nj = 0; nj < 8; ++nj) {
#pragma unroll
    for (int jj = 0; jj < 4; ++jj) {
      int qrow = q0 + wid * 16 + g * 4 + jj;
      int dcol = h * DHEAD + nj * 16 + c;
      ctx[(size_t)(b * SEQ + qrow) * HDIM + dcol] = f2bf(oacc[nj][jj] * inv[jj]);
    }
  }
}

// ---------------- launch ----------------
extern "C" void kernel_launch(void* const* d_in, const int* in_sizes, int n_in,
                              void* d_out, int out_size, void* d_ws, size_t ws_size,
                              hipStream_t stream) {
  const float* hs   = (const float*)d_in[0];
  const float* fcos = (const float*)d_in[1];
  const float* fsin = (const float*)d_in[2];
  const float* mask = (const float*)d_in[3];
  const float* Wq = (const float*)d_in[4];  const float* bq = (const float*)d_in[5];
  const float* Wk = (const float*)d_in[6];  const float* bk = (const float*)d_in[7];
  const float* Wv = (const float*)d_in[8];  const float* bv = (const float*)d_in[9];
  const float* Wo = (const float*)d_in[10]; const float* bo = (const float*)d_in[11];
  float* out = (float*)d_out;

  char* ws = (char*)d_ws;
  const size_t XB = (size_t)GM * HDIM * 2;    // 16 MB
  const size_t WB = (size_t)HDIM * HDIM * 2;  //  8 MB
  uint16_t* Xbf = (uint16_t*)(ws);            // reused as ctx after QKV
  uint16_t* Wqb = (uint16_t*)(ws + XB);       // Wqb..Wob contiguous (cvtw relies on it)
  uint16_t* Wkb = (uint16_t*)(ws + XB + WB);
  uint16_t* Wvb = (uint16_t*)(ws + XB + 2 * WB);
  uint16_t* Wob = (uint16_t*)(ws + XB + 3 * WB);
  uint16_t* qb  = (uint16_t*)(ws + XB + 4 * WB);
  uint16_t* kb  = (uint16_t*)(ws + XB + 4 * WB + XB);
  uint16_t* vb  = (uint16_t*)(ws + XB + 4 * WB + 2 * XB);

  cvt_kernel<<<4096, 256, 0, stream>>>(hs, Xbf, (GM * HDIM) / 8);
  cvtw_kernel<<<dim3(2048, 4), 256, 0, stream>>>(Wq, Wk, Wv, Wo, Wqb);

  gemm_qkv_kernel<<<dim3(GM / 128, GN / 128, 3), 256, 0, stream>>>(
      Xbf, Wqb, Wkb, Wvb, bq, bk, bv, qb, kb, vb);

  rope_kernel<<<dim3((GM * HDIM) / 8 / 256, 2, 1), 256, 0, stream>>>(qb, kb, fcos, fsin);

  attn_kernel<<<dim3(SEQ / 64, NHEAD, BATCH), 256, 0, stream>>>(qb, kb, vb, mask, Xbf);

  gemm_out_kernel<<<dim3(GM / 128, GN / 128, 1), 256, 0, stream>>>(Xbf, Wob, bo, out);
}

// Round 7
// 243.310 us; speedup vs baseline: 1.3786x; 1.1506x over previous
//
#include <hip/hip_runtime.h>
#include <stdint.h>

#define BATCH 4
#define SEQ   1024
#define NHEAD 16
#define DHEAD 128
#define HDIM  2048
#define GM    4096   /* BATCH*SEQ */
#define GN    2048
#define GK    2048

typedef __attribute__((ext_vector_type(8)))  short    short8;
typedef __attribute__((ext_vector_type(4)))  float    f32x4;
typedef __attribute__((ext_vector_type(16))) float    f32x16;
typedef __attribute__((ext_vector_type(4)))  uint32_t u32x4;

__device__ __forceinline__ uint16_t f2bf(float f) {
  uint32_t u = __builtin_bit_cast(uint32_t, f);
  u += 0x7fffu + ((u >> 16) & 1u);
  return (uint16_t)(u >> 16);
}
__device__ __forceinline__ float bf2f(uint16_t h) {
  return __builtin_bit_cast(float, (uint32_t)h << 16);
}
__device__ __forceinline__ uint32_t cvtpk(float lo, float hi) {
  uint32_t r;
  asm("v_cvt_pk_bf16_f32 %0, %1, %2" : "=v"(r) : "v"(lo), "v"(hi));
  return r;
}

// XOR swizzles (involutions) for 128B/256B LDS rows
__device__ __forceinline__ uint32_t swz128(uint32_t a) { return a ^ (((a >> 7) & 7u) << 4); }
__device__ __forceinline__ uint32_t swz256(uint32_t a) { return a ^ (((a >> 8) & 7u) << 4); }

#define GAS __attribute__((address_space(1)))
#define LAS __attribute__((address_space(3)))
__device__ __forceinline__ void gload_lds16(const void* g, void* l) {
  __builtin_amdgcn_global_load_lds((GAS const void*)g, (LAS void*)l, 16, 0, 0);
}

// ---------------- fp32 -> bf16 converts ----------------
__global__ void cvt_kernel(const float* __restrict__ in, uint16_t* __restrict__ out, int n8) {
  int i = blockIdx.x * 256 + threadIdx.x;
  if (i >= n8) return;
  const float4* p = (const float4*)in + (size_t)i * 2;
  float4 a = p[0], b = p[1];
  uint32_t w0 = f2bf(a.x) | ((uint32_t)f2bf(a.y) << 16);
  uint32_t w1 = f2bf(a.z) | ((uint32_t)f2bf(a.w) << 16);
  uint32_t w2 = f2bf(b.x) | ((uint32_t)f2bf(b.y) << 16);
  uint32_t w3 = f2bf(b.z) | ((uint32_t)f2bf(b.w) << 16);
  int4 r; r.x = (int)w0; r.y = (int)w1; r.z = (int)w2; r.w = (int)w3;
  *(int4*)(out + (size_t)i * 8) = r;
}

__global__ void cvtw_kernel(const float* __restrict__ W0, const float* __restrict__ W1,
                            const float* __restrict__ W2, const float* __restrict__ W3,
                            uint16_t* __restrict__ out) {
  const float* src = (blockIdx.y == 0) ? W0 : (blockIdx.y == 1) ? W1 : (blockIdx.y == 2) ? W2 : W3;
  int i = blockIdx.x * 256 + threadIdx.x;
  const float4* p = (const float4*)src + (size_t)i * 2;
  float4 a = p[0], b = p[1];
  uint32_t w0 = f2bf(a.x) | ((uint32_t)f2bf(a.y) << 16);
  uint32_t w1 = f2bf(a.z) | ((uint32_t)f2bf(a.w) << 16);
  uint32_t w2 = f2bf(b.x) | ((uint32_t)f2bf(b.y) << 16);
  uint32_t w3 = f2bf(b.z) | ((uint32_t)f2bf(b.w) << 16);
  int4 r; r.x = (int)w0; r.y = (int)w1; r.z = (int)w2; r.w = (int)w3;
  *(int4*)(out + (size_t)blockIdx.y * HDIM * HDIM + (size_t)i * 8) = r;
}

// ---------------- RoPE in-place on q/k ----------------
__global__ void rope_kernel(uint16_t* __restrict__ qb, uint16_t* __restrict__ kb,
                            const float* __restrict__ fcos, const float* __restrict__ fsin) {
  uint32_t i = blockIdx.x * 256 + threadIdx.x;
  uint16_t* p = (blockIdx.y == 0 ? qb : kb) + (size_t)i * 8;
  uint32_t e0 = i * 8;
  uint32_t row = e0 >> 11;
  uint32_t col = e0 & 2047;
  uint32_t s = row & (SEQ - 1);
  uint32_t pi = (col & (DHEAD - 1)) >> 1;
  float4 cv = *(const float4*)(fcos + (size_t)s * 64 + pi);
  float4 sv = *(const float4*)(fsin + (size_t)s * 64 + pi);
  int4 raw = *(const int4*)p;
  uint16_t u[8]; *(int4*)u = raw;
  float cc[4] = {cv.x, cv.y, cv.z, cv.w}, ss[4] = {sv.x, sv.y, sv.z, sv.w};
#pragma unroll
  for (int t = 0; t < 4; ++t) {
    float x0 = bf2f(u[2 * t]), x1 = bf2f(u[2 * t + 1]);
    float o0 = x0 * cc[t] - x1 * ss[t];
    float o1 = x0 * ss[t] + x1 * cc[t];
    u[2 * t] = f2bf(o0); u[2 * t + 1] = f2bf(o1);
  }
  *(int4*)p = *(int4*)u;
}

// ---------------- GEMM (BK=64, measured good): C = A(MxK) @ W(NxK)^T + bias ----------------
template <int MODE>
__device__ __forceinline__ void gemm_body(const uint16_t* __restrict__ A,
                                          const uint16_t* __restrict__ Bw,
                                          const float* __restrict__ bias,
                                          void* __restrict__ Cout) {
  __shared__ __align__(16) char smA[128 * 128];
  __shared__ __align__(16) char smB[128 * 128];
  const int tid = threadIdx.x, lane = tid & 63, wid = tid >> 6;
  const int c = lane & 15, g = lane >> 4;
  const int row0 = blockIdx.x * 128, col0 = blockIdx.y * 128;
  const int wr = wid >> 1, wc = wid & 1;
  f32x4 acc[4][4] = {};
  const uint32_t oBase = wid * 4096 + lane * 16;

  for (int kk = 0; kk < GK; kk += 64) {
#pragma unroll
    for (int q = 0; q < 4; ++q) {
      uint32_t o = oBase + q * 1024;
      uint32_t r = o >> 7;
      uint32_t cb = (o & 127) ^ ((r & 7u) << 4);
      gload_lds16((const char*)A + ((size_t)(row0 + r) * GK + kk) * 2 + cb,
                  smA + wid * 4096 + q * 1024);
      gload_lds16((const char*)Bw + ((size_t)(col0 + r) * GK + kk) * 2 + cb,
                  smB + wid * 4096 + q * 1024);
    }
    __syncthreads();
    short8 af[4][2], bf[4][2];
#pragma unroll
    for (int m = 0; m < 4; ++m) {
      const uint32_t row = (uint32_t)(wr * 64 + m * 16 + c);
#pragma unroll
      for (int ks = 0; ks < 2; ++ks)
        af[m][ks] = *(const short8*)(smA + row * 128 + (((uint32_t)(ks * 64 + g * 16)) ^ ((row & 7u) << 4)));
    }
#pragma unroll
    for (int n = 0; n < 4; ++n) {
      const uint32_t row = (uint32_t)(wc * 64 + n * 16 + c);
#pragma unroll
      for (int ks = 0; ks < 2; ++ks)
        bf[n][ks] = *(const short8*)(smB + row * 128 + (((uint32_t)(ks * 64 + g * 16)) ^ ((row & 7u) << 4)));
    }
#pragma unroll
    for (int m = 0; m < 4; ++m)
#pragma unroll
      for (int n = 0; n < 4; ++n)
#pragma unroll
        for (int ks = 0; ks < 2; ++ks)
          acc[m][n] = __builtin_amdgcn_mfma_f32_16x16x32_bf16(af[m][ks], bf[n][ks], acc[m][n], 0, 0, 0);
    __syncthreads();
  }

  float bn[4];
#pragma unroll
  for (int n = 0; n < 4; ++n) bn[n] = bias[col0 + wc * 64 + n * 16 + c];
#pragma unroll
  for (int m = 0; m < 4; ++m) {
    const int gr = row0 + wr * 64 + m * 16 + g * 4;
#pragma unroll
    for (int n = 0; n < 4; ++n) {
      const int gc = col0 + wc * 64 + n * 16 + c;
#pragma unroll
      for (int jj = 0; jj < 4; ++jj) {
        float v = acc[m][n][jj] + bn[n];
        if (MODE == 1) ((float*)Cout)[(size_t)(gr + jj) * GN + gc] = v;
        else           ((uint16_t*)Cout)[(size_t)(gr + jj) * GN + gc] = f2bf(v);
      }
    }
  }
}

__global__ __launch_bounds__(256, 2) void gemm_qkv_kernel(
    const uint16_t* __restrict__ X,
    const uint16_t* __restrict__ Wq, const uint16_t* __restrict__ Wk, const uint16_t* __restrict__ Wv,
    const float* __restrict__ bq, const float* __restrict__ bk, const float* __restrict__ bv,
    uint16_t* __restrict__ qo, uint16_t* __restrict__ ko, uint16_t* __restrict__ vo) {
  const uint16_t* W; const float* bias; uint16_t* out;
  if (blockIdx.z == 0)      { W = Wq; bias = bq; out = qo; }
  else if (blockIdx.z == 1) { W = Wk; bias = bk; out = ko; }
  else                      { W = Wv; bias = bv; out = vo; }
  gemm_body<0>(X, W, bias, out);
}

__global__ __launch_bounds__(256, 2) void gemm_out_kernel(
    const uint16_t* __restrict__ ctx, const uint16_t* __restrict__ Wo,
    const float* __restrict__ bo, float* __restrict__ out) {
  gemm_body<1>(ctx, Wo, bo, out);
}

// ---------------- flash attention v3b: 32x32 MFMA, in-register P (shfl exchange), XCD swizzle ----------------
// block = 128 q-rows x (h,b); 4 waves x 32 q-rows. grid 512 (=2/CU).
// LDS pool: smK [0,16K) [kv64][256B] swz256; smVT [16K,32K) [d128][128B] swz128;
//           mask [32K,32K+256); epilogue smT overlays [0,18432) in [q][d] orientation.
__global__ __launch_bounds__(256, 2) void attn_kernel(
    const uint16_t* __restrict__ q, const uint16_t* __restrict__ k,
    const uint16_t* __restrict__ v, const float* __restrict__ mask,
    uint16_t* __restrict__ ctx) {
  __shared__ __align__(16) char pool[33024];
  char* smK  = pool;
  char* smVT = pool + 16384;
  float* smMaskF = (float*)(pool + 32768);
  float* smT = (float*)pool;  // epilogue only

  const int tid = threadIdx.x, lane = tid & 63, wid = tid >> 6;
  const int c32 = lane & 31, hi = lane >> 5;
  // XCD-chunked swizzle: xcd = bid%8 gets a contiguous chunk of 64 logical blocks = 8 (b,h) pairs
  const int lb = (blockIdx.x & 7) * 64 + (blockIdx.x >> 3);
  const int qt = lb & 7, bh = lb >> 3;
  const int h = bh & (NHEAD - 1), b = bh >> 4;
  const int q0 = qt * 128;
  const float scale = 0.022097086912079608f;  // 1/sqrt(2048)

  // Q fragments in registers: B-frag[k = ks*16 + hi*8 + j][q = c32]
  short8 qreg[8];
  {
    const uint16_t* qrow = q + (size_t)(b * SEQ + q0 + wid * 32 + c32) * HDIM + h * DHEAD;
#pragma unroll
    for (int ks = 0; ks < 8; ++ks) qreg[ks] = *(const short8*)(qrow + ks * 16 + hi * 8);
  }

  const int kvg = tid >> 5;          // V-transpose: 8 kv x 4 d per thread
  const int d0v = (tid & 31) * 4;

  float mreg = -1e30f, lreg = 0.f;
  f32x16 o[4] = {};  // O^T tiles: [d = dt*32 + (r&3)+8*(r>>2)+4*hi][q = c32]

  for (int t = 0; t < 16; ++t) {
    const int kv0 = t * 64;
    __syncthreads();
    // stage K (64x128 bf16) via global_load_lds, pre-swizzled source
#pragma unroll
    for (int i = 0; i < 4; ++i) {
      uint32_t o_ = wid * 4096 + i * 1024 + lane * 16;
      uint32_t r = o_ >> 8;
      uint32_t cb = swz256(o_) & 255;
      gload_lds16((const char*)k + ((size_t)(b * SEQ + kv0 + r) * HDIM + h * DHEAD) * 2 + cb,
                  smK + wid * 4096 + i * 1024);
    }
    if (tid < 64) smMaskF[tid] = mask[b * SEQ + kv0 + tid];
    {  // V transpose into smVT[d][kv]
      const uint16_t* vsrc = v + (size_t)(b * SEQ + kv0 + kvg * 8) * HDIM + h * DHEAD + d0v;
      uint32_t vw[8][2];
#pragma unroll
      for (int e = 0; e < 8; ++e) {
        uint2 t2 = *(const uint2*)(vsrc + (size_t)e * HDIM);
        vw[e][0] = t2.x; vw[e][1] = t2.y;
      }
#pragma unroll
      for (int j = 0; j < 4; ++j) {
        const int hw = j >> 1, sh = (j & 1) * 16;
        int4 pk;
        pk.x = (int)(((vw[0][hw] >> sh) & 0xffffu) | (((vw[1][hw] >> sh) & 0xffffu) << 16));
        pk.y = (int)(((vw[2][hw] >> sh) & 0xffffu) | (((vw[3][hw] >> sh) & 0xffffu) << 16));
        pk.z = (int)(((vw[4][hw] >> sh) & 0xffffu) | (((vw[5][hw] >> sh) & 0xffffu) << 16));
        pk.w = (int)(((vw[6][hw] >> sh) & 0xffffu) | (((vw[7][hw] >> sh) & 0xffffu) << 16));
        *(int4*)(smVT + swz128((uint32_t)((d0v + j) * 128 + kvg * 16))) = pk;
      }
    }
    __syncthreads();

    // S^T = K @ Q^T : two 32x32 tiles (kv 0-31, 32-63) x 32 q-cols
    f32x16 st[2] = {};
#pragma unroll
    for (int ks = 0; ks < 8; ++ks) {
#pragma unroll
      for (int mi = 0; mi < 2; ++mi) {
        const uint32_t row = (uint32_t)(mi * 32 + c32);
        short8 kf = *(const short8*)(smK + row * 256 +
                    (((uint32_t)(ks * 32 + hi * 16)) ^ ((row & 7u) << 4)));
        st[mi] = __builtin_amdgcn_mfma_f32_32x32x16_bf16(kf, qreg[ks], st[mi], 0, 0, 0);
      }
    }

    // scale + mask + row max (lane owns q-col c32; kv rows (r&3)+8*(r>>2)+4*hi)
    float p[32];
    float pmax = -1e30f;
#pragma unroll
    for (int mi = 0; mi < 2; ++mi) {
      const float* mb = smMaskF + mi * 32 + hi * 4;
      float4 m0 = *(const float4*)(mb);
      float4 m1 = *(const float4*)(mb + 8);
      float4 m2 = *(const float4*)(mb + 16);
      float4 m3 = *(const float4*)(mb + 24);
      float mm[16] = {m0.x, m0.y, m0.z, m0.w, m1.x, m1.y, m1.z, m1.w,
                      m2.x, m2.y, m2.z, m2.w, m3.x, m3.y, m3.z, m3.w};
#pragma unroll
      for (int r = 0; r < 16; ++r) {
        float s = st[mi][r] * scale;
        if (mm[r] == 0.f) s = -1e9f;
        p[mi * 16 + r] = s;
        pmax = fmaxf(pmax, s);
      }
    }
    pmax = fmaxf(pmax, __shfl_xor(pmax, 32, 64));

    // defer-max rescale (T13)
    if (!__all(pmax <= mreg + 8.f)) {
      float mnew = fmaxf(mreg, pmax);
      float fac = __expf(mreg - mnew);
      lreg *= fac;
#pragma unroll
      for (int dt = 0; dt < 4; ++dt)
#pragma unroll
        for (int e = 0; e < 16; ++e) o[dt][e] *= fac;
      mreg = mnew;
    }

    // exp + pack to bf16 PV B-frags: cvt_pk pairs, cross-half exchange via shfl_xor(32)
    float rsum = 0.f;
    short8 pfrag[4];
#pragma unroll
    for (int mi = 0; mi < 2; ++mi) {
      float pe[16];
#pragma unroll
      for (int r = 0; r < 16; ++r) {
        pe[r] = __expf(p[mi * 16 + r] - mreg);
        rsum += pe[r];
      }
      uint32_t w[8], s[8];
#pragma unroll
      for (int j = 0; j < 8; ++j) w[j] = cvtpk(pe[2 * j], pe[2 * j + 1]);
#pragma unroll
      for (int j = 0; j < 8; ++j) s[j] = (uint32_t)__shfl_xor((int)w[j], 32, 64);
      // pfrag element j holds P[kv = e*16 + hi*8 + j]; own lane holds kv pairs (4hi+{0,1},...)
      u32x4 f0, f1;
      f0[0] = hi ? s[2] : w[0];  f0[1] = hi ? s[3] : w[1];
      f0[2] = hi ? w[2] : s[0];  f0[3] = hi ? w[3] : s[1];
      f1[0] = hi ? s[6] : w[4];  f1[1] = hi ? s[7] : w[5];
      f1[2] = hi ? w[6] : s[4];  f1[3] = hi ? w[7] : s[5];
      pfrag[mi * 2]     = __builtin_bit_cast(short8, f0);
      pfrag[mi * 2 + 1] = __builtin_bit_cast(short8, f1);
    }
    rsum += __shfl_xor(rsum, 32, 64);
    lreg += rsum;

    // O^T += V^T @ P : 4 d-tiles x 4 k-steps of 16 kv
#pragma unroll
    for (int dt = 0; dt < 4; ++dt) {
      const uint32_t row = (uint32_t)(dt * 32 + c32);
#pragma unroll
      for (int e = 0; e < 4; ++e) {
        short8 vf = *(const short8*)(smVT + row * 128 +
                    (((uint32_t)(e * 32 + hi * 16)) ^ ((row & 7u) << 4)));
        o[dt] = __builtin_amdgcn_mfma_f32_32x32x16_bf16(vf, pfrag[e], o[dt], 0, 0, 0);
      }
    }
  }

  // epilogue: normalize, transpose O^T -> O through LDS ([q][d] orientation), coalesced bf16 store
  const float linv = 1.f / lreg;
  float* myT = smT + wid * (32 * 36);
  const int qe = lane >> 1, de0 = (lane & 1) * 16;
#pragma unroll
  for (int dt = 0; dt < 4; ++dt) {
    __syncthreads();
#pragma unroll
    for (int r = 0; r < 16; ++r) {
      const int drow = (r & 3) + 8 * (r >> 2) + 4 * hi;
      myT[c32 * 36 + drow] = o[dt][r] * linv;   // [q][d]
    }
    asm volatile("s_waitcnt lgkmcnt(0)" ::: "memory");
    float vv[16];
#pragma unroll
    for (int j = 0; j < 4; ++j) {
      float4 rd = *(const float4*)(myT + qe * 36 + de0 + j * 4);  // [q=qe][d=de0..de0+15]
      vv[j * 4 + 0] = rd.x; vv[j * 4 + 1] = rd.y; vv[j * 4 + 2] = rd.z; vv[j * 4 + 3] = rd.w;
    }
    uint32_t pw[8];
#pragma unroll
    for (int m = 0; m < 8; ++m)
      pw[m] = f2bf(vv[2 * m]) | ((uint32_t)f2bf(vv[2 * m + 1]) << 16);
    uint16_t* dst = ctx + (size_t)(b * SEQ + q0 + wid * 32 + qe) * HDIM + h * DHEAD + dt * 32 + de0;
    int4 s0; s0.x = (int)pw[0]; s0.y = (int)pw[1]; s0.z = (int)pw[2]; s0.w = (int)pw[3];
    int4 s1; s1.x = (int)pw[4]; s1.y = (int)pw[5]; s1.z = (int)pw[6]; s1.w = (int)pw[7];
    *(int4*)(dst) = s0;
    *(int4*)(dst + 8) = s1;
  }
}

// ---------------- launch ----------------
extern "C" void kernel_launch(void* const* d_in, const int* in_sizes, int n_in,
                              void* d_out, int out_size, void* d_ws, size_t ws_size,
                              hipStream_t stream) {
  const float* hs   = (const float*)d_in[0];
  const float* fcos = (const float*)d_in[1];
  const float* fsin = (const float*)d_in[2];
  const float* mask = (const float*)d_in[3];
  const float* Wq = (const float*)d_in[4];  const float* bq = (const float*)d_in[5];
  const float* Wk = (const float*)d_in[6];  const float* bk = (const float*)d_in[7];
  const float* Wv = (const float*)d_in[8];  const float* bv = (const float*)d_in[9];
  const float* Wo = (const float*)d_in[10]; const float* bo = (const float*)d_in[11];
  float* out = (float*)d_out;

  char* ws = (char*)d_ws;
  const size_t XB = (size_t)GM * HDIM * 2;    // 16 MB
  const size_t WB = (size_t)HDIM * HDIM * 2;  //  8 MB
  uint16_t* Xbf = (uint16_t*)(ws);            // reused as ctx after QKV
  uint16_t* Wqb = (uint16_t*)(ws + XB);       // Wqb..Wob contiguous (cvtw relies on it)
  uint16_t* Wkb = (uint16_t*)(ws + XB + WB);
  uint16_t* Wvb = (uint16_t*)(ws + XB + 2 * WB);
  uint16_t* Wob = (uint16_t*)(ws + XB + 3 * WB);
  uint16_t* qb  = (uint16_t*)(ws + XB + 4 * WB);
  uint16_t* kb  = (uint16_t*)(ws + XB + 4 * WB + XB);
  uint16_t* vb  = (uint16_t*)(ws + XB + 4 * WB + 2 * XB);

  cvt_kernel<<<4096, 256, 0, stream>>>(hs, Xbf, (GM * HDIM) / 8);
  cvtw_kernel<<<dim3(2048, 4), 256, 0, stream>>>(Wq, Wk, Wv, Wo, Wqb);

  gemm_qkv_kernel<<<dim3(GM / 128, GN / 128, 3), 256, 0, stream>>>(
      Xbf, Wqb, Wkb, Wvb, bq, bk, bv, qb, kb, vb);

  rope_kernel<<<dim3((GM * HDIM) / 8 / 256, 2, 1), 256, 0, stream>>>(qb, kb, fcos, fsin);

  attn_kernel<<<512, 256, 0, stream>>>(qb, kb, vb, mask, Xbf);

  gemm_out_kernel<<<dim3(GM / 128, GN / 128, 1), 256, 0, stream>>>(Xbf, Wob, bo, out);
}

// Round 8
// 240.860 us; speedup vs baseline: 1.3927x; 1.0102x over previous
//
#include <hip/hip_runtime.h>
#include <stdint.h>

#define BATCH 4
#define SEQ   1024
#define NHEAD 16
#define DHEAD 128
#define HDIM  2048
#define GM    4096   /* BATCH*SEQ */
#define GN    2048
#define GK    2048

typedef __attribute__((ext_vector_type(8)))  short    short8;
typedef __attribute__((ext_vector_type(4)))  float    f32x4;
typedef __attribute__((ext_vector_type(16))) float    f32x16;
typedef __attribute__((ext_vector_type(4)))  uint32_t u32x4;

__device__ __forceinline__ uint16_t f2bf(float f) {
  uint32_t u = __builtin_bit_cast(uint32_t, f);
  u += 0x7fffu + ((u >> 16) & 1u);
  return (uint16_t)(u >> 16);
}
__device__ __forceinline__ float bf2f(uint16_t h) {
  return __builtin_bit_cast(float, (uint32_t)h << 16);
}
__device__ __forceinline__ uint32_t cvtpk(float lo, float hi) {
  uint32_t r;
  asm("v_cvt_pk_bf16_f32 %0, %1, %2" : "=v"(r) : "v"(lo), "v"(hi));
  return r;
}

// XOR swizzles (involutions) for 128B/256B LDS rows
__device__ __forceinline__ uint32_t swz128(uint32_t a) { return a ^ (((a >> 7) & 7u) << 4); }
__device__ __forceinline__ uint32_t swz256(uint32_t a) { return a ^ (((a >> 8) & 7u) << 4); }

#define GAS __attribute__((address_space(1)))
#define LAS __attribute__((address_space(3)))
__device__ __forceinline__ void gload_lds16(const void* g, void* l) {
  __builtin_amdgcn_global_load_lds((GAS const void*)g, (LAS void*)l, 16, 0, 0);
}

// ---------------- fp32 -> bf16 convert (hs + 4 weight matrices, one launch) ----------------
__global__ void cvt_all_kernel(const float* __restrict__ hs,
                               const float* __restrict__ W0, const float* __restrict__ W1,
                               const float* __restrict__ W2, const float* __restrict__ W3,
                               uint16_t* __restrict__ Xbf, uint16_t* __restrict__ Wb) {
  const int bid = blockIdx.x;
  const float* src; uint16_t* dst;
  if (bid < 4096) {
    src = hs + (size_t)bid * 2048;
    dst = Xbf + (size_t)bid * 2048;
  } else {
    const int m = (bid - 4096) >> 11;
    const int blk = (bid - 4096) & 2047;
    const float* Ws = (m == 0) ? W0 : (m == 1) ? W1 : (m == 2) ? W2 : W3;
    src = Ws + (size_t)blk * 2048;
    dst = Wb + (size_t)m * HDIM * HDIM + (size_t)blk * 2048;
  }
  const float4* p = (const float4*)src + (size_t)threadIdx.x * 2;
  float4 a = p[0], b = p[1];
  uint32_t w0 = f2bf(a.x) | ((uint32_t)f2bf(a.y) << 16);
  uint32_t w1 = f2bf(a.z) | ((uint32_t)f2bf(a.w) << 16);
  uint32_t w2 = f2bf(b.x) | ((uint32_t)f2bf(b.y) << 16);
  uint32_t w3 = f2bf(b.z) | ((uint32_t)f2bf(b.w) << 16);
  int4 r; r.x = (int)w0; r.y = (int)w1; r.z = (int)w2; r.w = (int)w3;
  *(int4*)(dst + (size_t)threadIdx.x * 8) = r;
}

// ---------------- RoPE in-place on q/k ----------------
__global__ void rope_kernel(uint16_t* __restrict__ qb, uint16_t* __restrict__ kb,
                            const float* __restrict__ fcos, const float* __restrict__ fsin) {
  uint32_t i = blockIdx.x * 256 + threadIdx.x;
  uint16_t* p = (blockIdx.y == 0 ? qb : kb) + (size_t)i * 8;
  uint32_t e0 = i * 8;
  uint32_t row = e0 >> 11;
  uint32_t col = e0 & 2047;
  uint32_t s = row & (SEQ - 1);
  uint32_t pi = (col & (DHEAD - 1)) >> 1;
  float4 cv = *(const float4*)(fcos + (size_t)s * 64 + pi);
  float4 sv = *(const float4*)(fsin + (size_t)s * 64 + pi);
  int4 raw = *(const int4*)p;
  uint16_t u[8]; *(int4*)u = raw;
  float cc[4] = {cv.x, cv.y, cv.z, cv.w}, ss[4] = {sv.x, sv.y, sv.z, sv.w};
#pragma unroll
  for (int t = 0; t < 4; ++t) {
    float x0 = bf2f(u[2 * t]), x1 = bf2f(u[2 * t + 1]);
    float o0 = x0 * cc[t] - x1 * ss[t];
    float o1 = x0 * ss[t] + x1 * cc[t];
    u[2 * t] = f2bf(o0); u[2 * t + 1] = f2bf(o1);
  }
  *(int4*)p = *(int4*)u;
}

// ---------------- GEMM (BK=64, measured 1005 TF): C = A(MxK) @ W(NxK)^T + bias ----------------
template <int MODE>
__device__ __forceinline__ void gemm_body(const uint16_t* __restrict__ A,
                                          const uint16_t* __restrict__ Bw,
                                          const float* __restrict__ bias,
                                          void* __restrict__ Cout) {
  __shared__ __align__(16) char smA[128 * 128];
  __shared__ __align__(16) char smB[128 * 128];
  const int tid = threadIdx.x, lane = tid & 63, wid = tid >> 6;
  const int c = lane & 15, g = lane >> 4;
  const int row0 = blockIdx.x * 128, col0 = blockIdx.y * 128;
  const int wr = wid >> 1, wc = wid & 1;
  f32x4 acc[4][4] = {};
  const uint32_t oBase = wid * 4096 + lane * 16;

  for (int kk = 0; kk < GK; kk += 64) {
#pragma unroll
    for (int q = 0; q < 4; ++q) {
      uint32_t o = oBase + q * 1024;
      uint32_t r = o >> 7;
      uint32_t cb = (o & 127) ^ ((r & 7u) << 4);
      gload_lds16((const char*)A + ((size_t)(row0 + r) * GK + kk) * 2 + cb,
                  smA + wid * 4096 + q * 1024);
      gload_lds16((const char*)Bw + ((size_t)(col0 + r) * GK + kk) * 2 + cb,
                  smB + wid * 4096 + q * 1024);
    }
    __syncthreads();
    short8 af[4][2], bf[4][2];
#pragma unroll
    for (int m = 0; m < 4; ++m) {
      const uint32_t row = (uint32_t)(wr * 64 + m * 16 + c);
#pragma unroll
      for (int ks = 0; ks < 2; ++ks)
        af[m][ks] = *(const short8*)(smA + row * 128 + (((uint32_t)(ks * 64 + g * 16)) ^ ((row & 7u) << 4)));
    }
#pragma unroll
    for (int n = 0; n < 4; ++n) {
      const uint32_t row = (uint32_t)(wc * 64 + n * 16 + c);
#pragma unroll
      for (int ks = 0; ks < 2; ++ks)
        bf[n][ks] = *(const short8*)(smB + row * 128 + (((uint32_t)(ks * 64 + g * 16)) ^ ((row & 7u) << 4)));
    }
#pragma unroll
    for (int m = 0; m < 4; ++m)
#pragma unroll
      for (int n = 0; n < 4; ++n)
#pragma unroll
        for (int ks = 0; ks < 2; ++ks)
          acc[m][n] = __builtin_amdgcn_mfma_f32_16x16x32_bf16(af[m][ks], bf[n][ks], acc[m][n], 0, 0, 0);
    __syncthreads();
  }

  float bn[4];
#pragma unroll
  for (int n = 0; n < 4; ++n) bn[n] = bias[col0 + wc * 64 + n * 16 + c];
#pragma unroll
  for (int m = 0; m < 4; ++m) {
    const int gr = row0 + wr * 64 + m * 16 + g * 4;
#pragma unroll
    for (int n = 0; n < 4; ++n) {
      const int gc = col0 + wc * 64 + n * 16 + c;
#pragma unroll
      for (int jj = 0; jj < 4; ++jj) {
        float v = acc[m][n][jj] + bn[n];
        if (MODE == 1) ((float*)Cout)[(size_t)(gr + jj) * GN + gc] = v;
        else           ((uint16_t*)Cout)[(size_t)(gr + jj) * GN + gc] = f2bf(v);
      }
    }
  }
}

__global__ __launch_bounds__(256, 2) void gemm_qkv_kernel(
    const uint16_t* __restrict__ X,
    const uint16_t* __restrict__ Wq, const uint16_t* __restrict__ Wk, const uint16_t* __restrict__ Wv,
    const float* __restrict__ bq, const float* __restrict__ bk, const float* __restrict__ bv,
    uint16_t* __restrict__ qo, uint16_t* __restrict__ ko, uint16_t* __restrict__ vo) {
  const uint16_t* W; const float* bias; uint16_t* out;
  if (blockIdx.z == 0)      { W = Wq; bias = bq; out = qo; }
  else if (blockIdx.z == 1) { W = Wk; bias = bk; out = ko; }
  else                      { W = Wv; bias = bv; out = vo; }
  gemm_body<0>(X, W, bias, out);
}

__global__ __launch_bounds__(256, 2) void gemm_out_kernel(
    const uint16_t* __restrict__ ctx, const uint16_t* __restrict__ Wo,
    const float* __restrict__ bo, float* __restrict__ out) {
  gemm_body<1>(ctx, Wo, bo, out);
}

// ---------------- flash attention v4: v3b + double-buffered pipelined staging ----------------
// block = 128 q-rows x (h,b); 4 waves x 32 q-rows; grid 512 (2/CU).
// LDS pool 66KB: bufK[2] 16KB [kv64][256B] swz256; bufVT[2] 16KB [d128][128B] swz128;
// mask[2] 256B. One barrier per kv-tile; stage(t+1) issued before compute(t).
// Epilogue smT overlays pool[0,18432) in [q][d] orientation.
__global__ __launch_bounds__(256, 2) void attn_kernel(
    const uint16_t* __restrict__ q, const uint16_t* __restrict__ k,
    const uint16_t* __restrict__ v, const float* __restrict__ mask,
    uint16_t* __restrict__ ctx) {
  __shared__ __align__(16) char pool[66048];
  float* smT = (float*)pool;  // epilogue only

  const int tid = threadIdx.x, lane = tid & 63, wid = tid >> 6;
  const int c32 = lane & 31, hi = lane >> 5;
  // XCD-chunked swizzle: xcd = bid%8 owns 8 complete (b,h) pairs (K/V ~4MB = one L2)
  const int lb = (blockIdx.x & 7) * 64 + (blockIdx.x >> 3);
  const int qt = lb & 7, bh = lb >> 3;
  const int h = bh & (NHEAD - 1), b = bh >> 4;
  const int q0 = qt * 128;
  const float scale = 0.022097086912079608f;  // 1/sqrt(2048)

  // Q fragments in registers: B-frag[k = ks*16 + hi*8 + j][q = c32]
  short8 qreg[8];
  {
    const uint16_t* qrow = q + (size_t)(b * SEQ + q0 + wid * 32 + c32) * HDIM + h * DHEAD;
#pragma unroll
    for (int ks = 0; ks < 8; ++ks) qreg[ks] = *(const short8*)(qrow + ks * 16 + hi * 8);
  }

  const int kvg = tid >> 5;          // V-transpose: 8 kv x 4 d per thread
  const int d0v = (tid & 31) * 4;

  // ---- staging helpers (buf = s&1) ----
  auto issueK = [&](int s) {
    char* dK = pool + (s & 1) * 16384;
#pragma unroll
    for (int i = 0; i < 4; ++i) {
      uint32_t o_ = wid * 4096 + i * 1024 + lane * 16;
      uint32_t r = o_ >> 8;
      uint32_t cb = swz256(o_) & 255;
      gload_lds16((const char*)k + ((size_t)(b * SEQ + s * 64 + r) * HDIM + h * DHEAD) * 2 + cb,
                  dK + wid * 4096 + i * 1024);
    }
  };
  auto loadV = [&](int s, uint32_t vw[8][2]) {
    const uint16_t* vsrc = v + (size_t)(b * SEQ + s * 64 + kvg * 8) * HDIM + h * DHEAD + d0v;
#pragma unroll
    for (int e = 0; e < 8; ++e) {
      uint2 t2 = *(const uint2*)(vsrc + (size_t)e * HDIM);
      vw[e][0] = t2.x; vw[e][1] = t2.y;
    }
  };
  auto writeVT = [&](int s, uint32_t vw[8][2]) {
    char* dVT = pool + 32768 + (s & 1) * 16384;
#pragma unroll
    for (int j = 0; j < 4; ++j) {
      const int hw = j >> 1, sh = (j & 1) * 16;
      int4 pk;
      pk.x = (int)(((vw[0][hw] >> sh) & 0xffffu) | (((vw[1][hw] >> sh) & 0xffffu) << 16));
      pk.y = (int)(((vw[2][hw] >> sh) & 0xffffu) | (((vw[3][hw] >> sh) & 0xffffu) << 16));
      pk.z = (int)(((vw[4][hw] >> sh) & 0xffffu) | (((vw[5][hw] >> sh) & 0xffffu) << 16));
      pk.w = (int)(((vw[6][hw] >> sh) & 0xffffu) | (((vw[7][hw] >> sh) & 0xffffu) << 16));
      *(int4*)(dVT + swz128((uint32_t)((d0v + j) * 128 + kvg * 16))) = pk;
    }
  };

  float mreg = -1e30f, lreg = 0.f;
  f32x16 o[4] = {};  // O^T tiles: [d = dt*32 + (r&3)+8*(r>>2)+4*hi][q = c32]

  // ---- prologue: stage tile 0 ----
  {
    float mtmp = 0.f;
    if (tid < 64) mtmp = mask[b * SEQ + tid];
    uint32_t vw[8][2];
    loadV(0, vw);
    issueK(0);
    if (tid < 64) ((float*)(pool + 65536))[tid] = mtmp;
    writeVT(0, vw);
  }
  __syncthreads();  // drains K gloads + LDS writes

  for (int t = 0; t < 16; ++t) {
    const int cur = t & 1;
    const char* sK  = pool + cur * 16384;
    const char* sVT = pool + 32768 + cur * 16384;
    const float* smMaskF = (const float*)(pool + 65536 + cur * 256);

    // ---- issue staging for t+1 (loads fly under compute) ----
    float mtmp = 0.f;
    uint32_t vw[8][2];
    if (t < 15) {
      if (tid < 64) mtmp = mask[b * SEQ + (t + 1) * 64 + tid];
      loadV(t + 1, vw);
      issueK(t + 1);
    }

    // ---- S^T = K @ Q^T : two 32x32 tiles x 32 q-cols ----
    f32x16 st[2] = {};
#pragma unroll
    for (int ks = 0; ks < 8; ++ks) {
#pragma unroll
      for (int mi = 0; mi < 2; ++mi) {
        const uint32_t row = (uint32_t)(mi * 32 + c32);
        short8 kf = *(const short8*)(sK + row * 256 +
                    (((uint32_t)(ks * 32 + hi * 16)) ^ ((row & 7u) << 4)));
        st[mi] = __builtin_amdgcn_mfma_f32_32x32x16_bf16(kf, qreg[ks], st[mi], 0, 0, 0);
      }
    }

    // ---- scale + mask + row max ----
    float p[32];
    float pmax = -1e30f;
#pragma unroll
    for (int mi = 0; mi < 2; ++mi) {
      const float* mb = smMaskF + mi * 32 + hi * 4;
      float4 m0 = *(const float4*)(mb);
      float4 m1 = *(const float4*)(mb + 8);
      float4 m2 = *(const float4*)(mb + 16);
      float4 m3 = *(const float4*)(mb + 24);
      float mm[16] = {m0.x, m0.y, m0.z, m0.w, m1.x, m1.y, m1.z, m1.w,
                      m2.x, m2.y, m2.z, m2.w, m3.x, m3.y, m3.z, m3.w};
#pragma unroll
      for (int r = 0; r < 16; ++r) {
        float s = st[mi][r] * scale;
        if (mm[r] == 0.f) s = -1e9f;
        p[mi * 16 + r] = s;
        pmax = fmaxf(pmax, s);
      }
    }
    pmax = fmaxf(pmax, __shfl_xor(pmax, 32, 64));

    // defer-max rescale (T13)
    if (!__all(pmax <= mreg + 8.f)) {
      float mnew = fmaxf(mreg, pmax);
      float fac = __expf(mreg - mnew);
      lreg *= fac;
#pragma unroll
      for (int dt = 0; dt < 4; ++dt)
#pragma unroll
        for (int e = 0; e < 16; ++e) o[dt][e] *= fac;
      mreg = mnew;
    }

    // ---- exp + pack to PV B-frags (cvt_pk + shfl_xor(32) exchange) ----
    float rsum = 0.f;
    short8 pfrag[4];
#pragma unroll
    for (int mi = 0; mi < 2; ++mi) {
      float pe[16];
#pragma unroll
      for (int r = 0; r < 16; ++r) {
        pe[r] = __expf(p[mi * 16 + r] - mreg);
        rsum += pe[r];
      }
      uint32_t w[8], s[8];
#pragma unroll
      for (int j = 0; j < 8; ++j) w[j] = cvtpk(pe[2 * j], pe[2 * j + 1]);
#pragma unroll
      for (int j = 0; j < 8; ++j) s[j] = (uint32_t)__shfl_xor((int)w[j], 32, 64);
      u32x4 f0, f1;
      f0[0] = hi ? s[2] : w[0];  f0[1] = hi ? s[3] : w[1];
      f0[2] = hi ? w[2] : s[0];  f0[3] = hi ? w[3] : s[1];
      f1[0] = hi ? s[6] : w[4];  f1[1] = hi ? s[7] : w[5];
      f1[2] = hi ? w[6] : s[4];  f1[3] = hi ? w[7] : s[5];
      pfrag[mi * 2]     = __builtin_bit_cast(short8, f0);
      pfrag[mi * 2 + 1] = __builtin_bit_cast(short8, f1);
    }
    rsum += __shfl_xor(rsum, 32, 64);
    lreg += rsum;

    // ---- write arrived V/mask for t+1 into buf^1 (K gloads still in flight) ----
    if (t < 15) {
      if (tid < 64) ((float*)(pool + 65536 + ((t + 1) & 1) * 256))[tid] = mtmp;
      writeVT(t + 1, vw);
    }

    // ---- O^T += V^T @ P ----
#pragma unroll
    for (int dt = 0; dt < 4; ++dt) {
      const uint32_t row = (uint32_t)(dt * 32 + c32);
#pragma unroll
      for (int e = 0; e < 4; ++e) {
        short8 vf = *(const short8*)(sVT + row * 128 +
                    (((uint32_t)(e * 32 + hi * 16)) ^ ((row & 7u) << 4)));
        o[dt] = __builtin_amdgcn_mfma_f32_32x32x16_bf16(vf, pfrag[e], o[dt], 0, 0, 0);
      }
    }

    __syncthreads();  // drains K(t+1) gloads + VT/mask writes; gates buf swap
  }

  // ---- epilogue: normalize, transpose O^T -> O via wave-private LDS, coalesced store ----
  const float linv = 1.f / lreg;
  float* myT = smT + wid * (32 * 36);
  const int qe = lane >> 1, de0 = (lane & 1) * 16;
#pragma unroll
  for (int dt = 0; dt < 4; ++dt) {
#pragma unroll
    for (int r = 0; r < 16; ++r) {
      const int drow = (r & 3) + 8 * (r >> 2) + 4 * hi;
      myT[c32 * 36 + drow] = o[dt][r] * linv;   // [q][d]
    }
    float vv[16];
#pragma unroll
    for (int j = 0; j < 4; ++j) {
      float4 rd = *(const float4*)(myT + qe * 36 + de0 + j * 4);
      vv[j * 4 + 0] = rd.x; vv[j * 4 + 1] = rd.y; vv[j * 4 + 2] = rd.z; vv[j * 4 + 3] = rd.w;
    }
    uint32_t pw[8];
#pragma unroll
    for (int m = 0; m < 8; ++m)
      pw[m] = f2bf(vv[2 * m]) | ((uint32_t)f2bf(vv[2 * m + 1]) << 16);
    uint16_t* dst = ctx + (size_t)(b * SEQ + q0 + wid * 32 + qe) * HDIM + h * DHEAD + dt * 32 + de0;
    int4 s0; s0.x = (int)pw[0]; s0.y = (int)pw[1]; s0.z = (int)pw[2]; s0.w = (int)pw[3];
    int4 s1; s1.x = (int)pw[4]; s1.y = (int)pw[5]; s1.z = (int)pw[6]; s1.w = (int)pw[7];
    *(int4*)(dst) = s0;
    *(int4*)(dst + 8) = s1;
  }
}

// ---------------- launch ----------------
extern "C" void kernel_launch(void* const* d_in, const int* in_sizes, int n_in,
                              void* d_out, int out_size, void* d_ws, size_t ws_size,
                              hipStream_t stream) {
  const float* hs   = (const float*)d_in[0];
  const float* fcos = (const float*)d_in[1];
  const float* fsin = (const float*)d_in[2];
  const float* mask = (const float*)d_in[3];
  const float* Wq = (const float*)d_in[4];  const float* bq = (const float*)d_in[5];
  const float* Wk = (const float*)d_in[6];  const float* bk = (const float*)d_in[7];
  const float* Wv = (const float*)d_in[8];  const float* bv = (const float*)d_in[9];
  const float* Wo = (const float*)d_in[10]; const float* bo = (const float*)d_in[11];
  float* out = (float*)d_out;

  char* ws = (char*)d_ws;
  const size_t XB = (size_t)GM * HDIM * 2;    // 16 MB
  const size_t WB = (size_t)HDIM * HDIM * 2;  //  8 MB
  uint16_t* Xbf = (uint16_t*)(ws);            // reused as ctx after QKV
  uint16_t* Wqb = (uint16_t*)(ws + XB);       // Wqb..Wob contiguous
  uint16_t* Wkb = (uint16_t*)(ws + XB + WB);
  uint16_t* Wvb = (uint16_t*)(ws + XB + 2 * WB);
  uint16_t* Wob = (uint16_t*)(ws + XB + 3 * WB);
  uint16_t* qb  = (uint16_t*)(ws + XB + 4 * WB);
  uint16_t* kb  = (uint16_t*)(ws + XB + 4 * WB + XB);
  uint16_t* vb  = (uint16_t*)(ws + XB + 4 * WB + 2 * XB);

  cvt_all_kernel<<<12288, 256, 0, stream>>>(hs, Wq, Wk, Wv, Wo, Xbf, Wqb);

  gemm_qkv_kernel<<<dim3(GM / 128, GN / 128, 3), 256, 0, stream>>>(
      Xbf, Wqb, Wkb, Wvb, bq, bk, bv, qb, kb, vb);

  rope_kernel<<<dim3((GM * HDIM) / 8 / 256, 2, 1), 256, 0, stream>>>(qb, kb, fcos, fsin);

  attn_kernel<<<512, 256, 0, stream>>>(qb, kb, vb, mask, Xbf);

  gemm_out_kernel<<<dim3(GM / 128, GN / 128, 1), 256, 0, stream>>>(Xbf, Wob, bo, out);
}